// Round 14
// baseline (801.101 us; speedup 1.0000x reference)
//
#include <hip/hip_runtime.h>
#include <math.h>

#define DIM 1024
#define P0 512
#define H 16
#define HD 64
#define B 2
#define S 1024
#define PT 1536   // P0 + S

typedef __attribute__((ext_vector_type(8))) short short8v;    // bf16 MFMA frag
typedef __attribute__((ext_vector_type(4))) float f32x4;
typedef __attribute__((ext_vector_type(8))) unsigned short ushort8v;
typedef __attribute__((ext_vector_type(4))) unsigned short ushort4v;
typedef unsigned long long ull;
struct ull2 { ull a, b; };   // 16B carrier for short8v bit_cast

__device__ __forceinline__ unsigned short bf16_rne(float x) {
  unsigned u = __builtin_bit_cast(unsigned, x);
  u += 0x7FFFu + ((u >> 16) & 1u);
  return (unsigned short)(u >> 16);
}
__device__ __forceinline__ float bf16_f(unsigned short h) {
  unsigned u = ((unsigned)h) << 16;
  return __builtin_bit_cast(float, u);
}

// ---------------------------------------------------------------- mag ----
__global__ __launch_bounds__(256) void k_mag(const float* __restrict__ zr,
                                             const float* __restrict__ zi,
                                             float* __restrict__ mag, int n4) {
  int i = blockIdx.x * blockDim.x + threadIdx.x;
  if (i < n4) {
    float4 a = ((const float4*)zr)[i];
    float4 b = ((const float4*)zi)[i];
    float4 o;
    o.x = sqrtf(a.x * a.x + b.x * b.x);
    o.y = sqrtf(a.y * a.y + b.y * b.y);
    o.z = sqrtf(a.z * a.z + b.z * b.z);
    o.w = sqrtf(a.w * a.w + b.w * b.w);
    ((float4*)mag)[i] = o;
  }
}

// -------------------------------- pattern + hi/lo split (fused) ----------
__global__ __launch_bounds__(256) void k_patt_split(const float* __restrict__ stored,
                                                    const float* __restrict__ mag,
                                                    unsigned short* __restrict__ phi,
                                                    unsigned short* __restrict__ plo,
                                                    int n4) {
  int i = blockIdx.x * blockDim.x + threadIdx.x;
  if (i >= n4) return;
  int d4 = i & (DIM / 4 - 1);
  int p  = (i >> 8) % PT;
  int b  = i / (PT * (DIM / 4));
  float4 v;
  if (p < P0) {
    v = ((const float4*)stored)[(size_t)p * (DIM / 4) + d4];
  } else {
    v = ((const float4*)mag)[((size_t)(b * S + (p - P0))) * (DIM / 4) + d4];
  }
  float xs[4] = {v.x, v.y, v.z, v.w};
  ushort4v hv, lv;
#pragma unroll
  for (int j = 0; j < 4; ++j) {
    unsigned short hb = bf16_rne(xs[j]);
    hv[j] = hb;
    lv[j] = bf16_rne(xs[j] - bf16_f(hb));
  }
  ((ushort4v*)phi)[(size_t)i] = hv;
  ((ushort4v*)plo)[(size_t)i] = lv;
}

// ---------------------------------------------- plain hi/lo bf16 split ----
__global__ __launch_bounds__(256) void k_split_plain(const float* __restrict__ X,
                                                     unsigned short* __restrict__ hi,
                                                     unsigned short* __restrict__ lo,
                                                     int n4) {
  int i = blockIdx.x * 256 + threadIdx.x;
  if (i >= n4) return;
  float4 v = ((const float4*)X)[(size_t)i];
  float xs[4] = {v.x, v.y, v.z, v.w};
  ushort4v hv, lv;
#pragma unroll
  for (int j = 0; j < 4; ++j) {
    unsigned short hb = bf16_rne(xs[j]);
    hv[j] = hb;
    lv[j] = bf16_rne(xs[j] - bf16_f(hb));
  }
  ((ushort4v*)hi)[(size_t)i] = hv;
  ((ushort4v*)lo)[(size_t)i] = lv;
}

// ------------------------------------------------------- MFMA GEMM --------
// C(M,N) = A @ W^T with A,W pre-split hi/lo bf16 row-major (K-contig).
// 128x128 tile, BK=32, 256 threads = 4 waves (2x2), 3-product split.
__global__ __launch_bounds__(256, 2) void k_gemm_mfma(
    const unsigned short* __restrict__ Ah, const unsigned short* __restrict__ Al,
    const unsigned short* __restrict__ Wh, const unsigned short* __restrict__ Wl,
    const float* __restrict__ bias, float* __restrict__ Cf,
    unsigned short* __restrict__ Ohi, unsigned short* __restrict__ Olo,
    int M, int N, int K, int mode, int rpb, int aremap) {
  __shared__ short8v lds[4][4 * 132];   // Ah, Al, Wh, Wl frag-major tiles
  const int t = threadIdx.x;
  const int w = t >> 6, lane = t & 63;
  const int l16 = lane & 15, l4 = lane >> 4;
  const int wr = w >> 1, wc = w & 1;
  const int bm = blockIdx.y, bn = blockIdx.x;

  f32x4 acc[4][4];
#pragma unroll
  for (int mi = 0; mi < 4; ++mi)
#pragma unroll
    for (int nj = 0; nj < 4; ++nj) acc[mi][nj] = (f32x4){0.f, 0.f, 0.f, 0.f};

  for (int k0 = 0; k0 < K; k0 += 32) {
    __syncthreads();
#pragma unroll
    for (int rep = 0; rep < 2; ++rep) {
      int u = rep * 256 + t;
      int kb = u & 3, r = u >> 2;
      int agr = bm * 128 + r;
      int ar = aremap ? (agr + 512 + ((agr >> 10) << 9)) : agr;
      size_t ga = (size_t)ar * K + k0 + kb * 8;
      size_t gw = (size_t)(bn * 128 + r) * K + k0 + kb * 8;
      int li = kb * 132 + r;
      lds[0][li] = *(const short8v*)(Ah + ga);
      lds[1][li] = *(const short8v*)(Al + ga);
      lds[2][li] = *(const short8v*)(Wh + gw);
      lds[3][li] = *(const short8v*)(Wl + gw);
    }
    __syncthreads();
    short8v af[4][2], bf[4][2];
#pragma unroll
    for (int mi = 0; mi < 4; ++mi) {
      int li = l4 * 132 + wr * 64 + mi * 16 + l16;
      af[mi][0] = lds[0][li];
      af[mi][1] = lds[1][li];
    }
#pragma unroll
    for (int nj = 0; nj < 4; ++nj) {
      int li = l4 * 132 + wc * 64 + nj * 16 + l16;
      bf[nj][0] = lds[2][li];
      bf[nj][1] = lds[3][li];
    }
#pragma unroll
    for (int mi = 0; mi < 4; ++mi)
#pragma unroll
      for (int nj = 0; nj < 4; ++nj) {
        acc[mi][nj] = __builtin_amdgcn_mfma_f32_16x16x32_bf16(af[mi][0], bf[nj][0], acc[mi][nj], 0, 0, 0);
        acc[mi][nj] = __builtin_amdgcn_mfma_f32_16x16x32_bf16(af[mi][0], bf[nj][1], acc[mi][nj], 0, 0, 0);
        acc[mi][nj] = __builtin_amdgcn_mfma_f32_16x16x32_bf16(af[mi][1], bf[nj][0], acc[mi][nj], 0, 0, 0);
      }
  }

#pragma unroll
  for (int mi = 0; mi < 4; ++mi)
#pragma unroll
    for (int nj = 0; nj < 4; ++nj)
#pragma unroll
      for (int i = 0; i < 4; ++i) {
        int rg = bm * 128 + wr * 64 + mi * 16 + l4 * 4 + i;
        int c  = bn * 128 + wc * 64 + nj * 16 + l16;
        float v = acc[mi][nj][i];
        if (mode == 0) {
          Cf[(size_t)rg * N + c] = v + (bias ? bias[c] : 0.f);
        } else {
          int b = rg >= rpb ? 1 : 0;
          int p = rg - b * rpb;
          int hh = c >> 6, d = c & 63;
          size_t o = (mode == 1)
                         ? ((((size_t)(b * 16 + hh)) * rpb + p) * 64 + d)
                         : ((((size_t)(b * 16 + hh)) * 64 + d) * (size_t)rpb + p);
          unsigned short hb = bf16_rne(v);
          Ohi[o] = hb;
          Olo[o] = bf16_rne(v - bf16_f(hb));
        }
      }
}

// ------------------------------------------------- MFMA attention step ----
// One Hopfield iteration. Block = 16 query rows of one (b,h), 8 waves.
// Swapped QK^T; interleaved tile ownership. BRANCH-FREE QK^T and PV:
// fully-masked tiles flow through as z=-1e9 -> weights=0 -> MFMA adds 0
// (bitwise-identical output); straight-line unrolled loops let the
// compiler pipeline the K/V L2 loads across MFMAs (the round-13 counters
// showed ~60% dual-pipe idle = exposed load latency behind the old
// wave-uniform `continue` branches). Scan guards kept (VALU savings,
// no loads blocked). Pair-0 V prefetched before Michelot (tau-indep).
// Sparsemax: 1 max + 7 Michelot from tau0=gmax-1 (exact).
// __launch_bounds__(512,4): HARD (rounds 6 & 10 spilled under tighter
// caps). Spill sentinel: WRITE_SIZE must stay ~16 MB/dispatch.
__global__ __launch_bounds__(512, 4) void k_attn_mfma(
    const unsigned short* __restrict__ shi, const unsigned short* __restrict__ slo,
    const unsigned short* __restrict__ khi, const unsigned short* __restrict__ klo,
    const unsigned short* __restrict__ vthi, const unsigned short* __restrict__ vtlo,
    const float* __restrict__ log_temp,
    unsigned short* __restrict__ swhi, unsigned short* __restrict__ swlo,
    unsigned short* __restrict__ ohi, unsigned short* __restrict__ olo) {
  __shared__ float part[8][2][2][20];             // 5120 B reduction scratch
  __shared__ float red[8][16][68];                // 34816 B full-width reduce
  const int t = threadIdx.x;
  const int w = t >> 6, lane = t & 63;
  const int l16 = lane & 15, l4 = lane >> 4;
  // XCD-aware bijective swizzle (2048 % 8 == 0)
  const int bid = blockIdx.x;
  const int tile = (bid & 7) * 256 + (bid >> 3);
  const int stile = tile & 63;
  const int bh = tile >> 6;
  const int h = bh & 15;
  const int s0 = stile * 16;
  const int maxTile = stile + 33;   // tile pt unmasked iff pt <= maxTile

  float lt = log_temp[h];
  lt = fminf(fmaxf(lt, -4.f), 4.f);
  const float inv_scale = 1.f / (8.f * expf(lt));

  // state B-fragments (swapped mfma): col = l16 = query row, k = 8*l4+j
  const size_t arow = ((size_t)bh * S + s0 + l16) * HD + 8 * l4;
  short8v ahi0 = *(const short8v*)(shi + arow);
  short8v ahi1 = *(const short8v*)(shi + arow + 32);
  short8v alo0 = *(const short8v*)(slo + arow);
  short8v alo1 = *(const short8v*)(slo + arow + 32);

  const size_t kb = (size_t)bh * PT * HD;
  const size_t vb = (size_t)bh * HD * PT;
  const int sg = s0 + l16;

  // ---- QK^T (swapped, interleaved tiles, BRANCH-FREE) ----
  float z0[6][4], z1[6][4];
#pragma unroll
  for (int j = 0; j < 6; ++j) {
    const int tA = w + 16 * j, tB = tA + 8;
    const size_t k0 = kb + ((size_t)(tA * 16 + l16)) * HD + 8 * l4;
    const size_t k1 = kb + ((size_t)(tB * 16 + l16)) * HD + 8 * l4;
    f32x4 a0 = {0.f, 0.f, 0.f, 0.f}, a1 = {0.f, 0.f, 0.f, 0.f};
    {
      short8v b00 = *(const short8v*)(khi + k0);
      short8v b01 = *(const short8v*)(khi + k0 + 32);
      short8v c00 = *(const short8v*)(klo + k0);
      short8v c01 = *(const short8v*)(klo + k0 + 32);
      a0 = __builtin_amdgcn_mfma_f32_16x16x32_bf16(b00, ahi0, a0, 0, 0, 0);
      a0 = __builtin_amdgcn_mfma_f32_16x16x32_bf16(b01, ahi1, a0, 0, 0, 0);
      a0 = __builtin_amdgcn_mfma_f32_16x16x32_bf16(b00, alo0, a0, 0, 0, 0);
      a0 = __builtin_amdgcn_mfma_f32_16x16x32_bf16(b01, alo1, a0, 0, 0, 0);
      a0 = __builtin_amdgcn_mfma_f32_16x16x32_bf16(c00, ahi0, a0, 0, 0, 0);
      a0 = __builtin_amdgcn_mfma_f32_16x16x32_bf16(c01, ahi1, a0, 0, 0, 0);
    }
    {
      short8v b10 = *(const short8v*)(khi + k1);
      short8v b11 = *(const short8v*)(khi + k1 + 32);
      short8v c10 = *(const short8v*)(klo + k1);
      short8v c11 = *(const short8v*)(klo + k1 + 32);
      a1 = __builtin_amdgcn_mfma_f32_16x16x32_bf16(b10, ahi0, a1, 0, 0, 0);
      a1 = __builtin_amdgcn_mfma_f32_16x16x32_bf16(b11, ahi1, a1, 0, 0, 0);
      a1 = __builtin_amdgcn_mfma_f32_16x16x32_bf16(b10, alo0, a1, 0, 0, 0);
      a1 = __builtin_amdgcn_mfma_f32_16x16x32_bf16(b11, alo1, a1, 0, 0, 0);
      a1 = __builtin_amdgcn_mfma_f32_16x16x32_bf16(c10, ahi0, a1, 0, 0, 0);
      a1 = __builtin_amdgcn_mfma_f32_16x16x32_bf16(c11, ahi1, a1, 0, 0, 0);
    }
#pragma unroll
    for (int i = 0; i < 4; ++i) {
      const int pA = tA * 16 + l4 * 4 + i;
      const int pB = tB * 16 + l4 * 4 + i;
      z0[j][i] = (pA > P0 + sg) ? -1e9f : a0[i] * inv_scale;
      z1[j][i] = (pB > P0 + sg) ? -1e9f : a1[i] * inv_scale;
    }
  }

  // ---- prefetch pair-0 V (tau-independent; hides Michelot latency) ----
  short8v pvh[4], pvl[4];
  {
    const int tA = w, tB = w + 8;
    const int pbase = (l4 < 2) ? (tA * 16 + 8 * l4) : (tB * 16 + 8 * (l4 - 2));
#pragma unroll
    for (int dt = 0; dt < 4; ++dt) {
      const size_t vo = vb + (size_t)(dt * 16 + l16) * PT + pbase;
      pvh[dt] = *(const short8v*)(vthi + vo);
      pvl[dt] = *(const short8v*)(vtlo + vo);
    }
  }

  // ---- row max (scalar per lane; dual chains; guarded scans) ----
  float mA = -1e30f, mB = -1e30f;
#pragma unroll
  for (int j = 0; j < 6; ++j) {
    if (w + 16 * j <= maxTile) {
#pragma unroll
      for (int i = 0; i < 4; ++i) {
        mA = fmaxf(mA, z0[j][i]);
        mB = fmaxf(mB, z1[j][i]);
      }
    }
  }
  float mxv = fmaxf(mA, mB);
  mxv = fmaxf(mxv, __shfl_xor(mxv, 16, 64));
  mxv = fmaxf(mxv, __shfl_xor(mxv, 32, 64));
  if (lane < 16) part[w][0][0][lane] = mxv;
  __syncthreads();
  float gm = -1e30f;
#pragma unroll
  for (int ww = 0; ww < 8; ++ww) gm = fmaxf(gm, part[ww][0][0][l16]);

  // ---- Michelot from tau0 = gmax-1: 7 rounds, dual-chain scans ----
  float tau = gm - 1.f;
  for (int it = 0; it < 7; ++it) {
    const int sl = (it + 1) & 1;
    float ca = 0.f, cb = 0.f, sa = 0.f, sb = 0.f;
#pragma unroll
    for (int j = 0; j < 6; ++j) {
      if (w + 16 * j <= maxTile) {
#pragma unroll
        for (int i = 0; i < 4; ++i) {
          float a = z0[j][i];
          if (a > tau) { ca += 1.f; sa += a; }
          float b2 = z1[j][i];
          if (b2 > tau) { cb += 1.f; sb += b2; }
        }
      }
    }
    float c = ca + cb, s = sa + sb;
    c += __shfl_xor(c, 16, 64);
    c += __shfl_xor(c, 32, 64);
    s += __shfl_xor(s, 16, 64);
    s += __shfl_xor(s, 32, 64);
    if (lane < 16) {
      part[w][sl][0][lane] = c;
      part[w][sl][1][lane] = s;
    }
    __syncthreads();
    float rc = 0.f, rs = 0.f;
#pragma unroll
    for (int ww = 0; ww < 8; ++ww) {
      rc += part[ww][sl][0][l16];
      rs += part[ww][sl][1][l16];
    }
    tau = (rs - 1.f) / rc;
  }

  // ---- PV: in-register weight exchange (shfl) + 3-product MFMA ----
  // BRANCH-FREE: masked tiles carry zero weights -> MFMA adds 0.
  f32x4 acc[4];
#pragma unroll
  for (int dt = 0; dt < 4; ++dt) acc[dt] = (f32x4){0.f, 0.f, 0.f, 0.f};
#pragma unroll
  for (int kk = 0; kk < 6; ++kk) {
    const int tA = w + 16 * kk, tB = tA + 8;
    ushort4v h0v, l0v, h1v, l1v;
#pragma unroll
    for (int i = 0; i < 4; ++i) {
      float w0 = fmaxf(z0[kk][i] - tau, 0.f);
      float w1 = fmaxf(z1[kk][i] - tau, 0.f);
      unsigned short hb0 = bf16_rne(w0);
      unsigned short hb1 = bf16_rne(w1);
      h0v[i] = hb0; l0v[i] = bf16_rne(w0 - bf16_f(hb0));
      h1v[i] = hb1; l1v[i] = bf16_rne(w1 - bf16_f(hb1));
    }
    const ull P0v = __builtin_bit_cast(ull, h0v);
    const ull P1v = __builtin_bit_cast(ull, h1v);
    const ull Q0v = __builtin_bit_cast(ull, l0v);
    const ull Q1v = __builtin_bit_cast(ull, l1v);
    const int srcA = l16 + 16 * (2 * (l4 & 1));
    const int srcB = srcA + 16;
    ull a0 = __shfl(P0v, srcA, 64);
    ull a1 = __shfl(P1v, srcA, 64);
    ull b0 = __shfl(P0v, srcB, 64);
    ull b1 = __shfl(P1v, srcB, 64);
    ull qa0 = __shfl(Q0v, srcA, 64);
    ull qa1 = __shfl(Q1v, srcA, 64);
    ull qb0 = __shfl(Q0v, srcB, 64);
    ull qb1 = __shfl(Q1v, srcB, 64);
    ull2 th = { (l4 < 2) ? a0 : a1, (l4 < 2) ? b0 : b1 };
    ull2 tl = { (l4 < 2) ? qa0 : qa1, (l4 < 2) ? qb0 : qb1 };
    short8v wah = __builtin_bit_cast(short8v, th);
    short8v wal = __builtin_bit_cast(short8v, tl);
    // permuted k-order: lanes l4<2 read tile A's p-range, l4>=2 tile B's
    const int pbase = (l4 < 2) ? (tA * 16 + 8 * l4) : (tB * 16 + 8 * (l4 - 2));
#pragma unroll
    for (int dt = 0; dt < 4; ++dt) {
      short8v vh, vl;
      if (kk == 0) {
        vh = pvh[dt];
        vl = pvl[dt];
      } else {
        const size_t vo = vb + (size_t)(dt * 16 + l16) * PT + pbase;
        vh = *(const short8v*)(vthi + vo);
        vl = *(const short8v*)(vtlo + vo);
      }
      acc[dt] = __builtin_amdgcn_mfma_f32_16x16x32_bf16(wah, vh, acc[dt], 0, 0, 0);
      acc[dt] = __builtin_amdgcn_mfma_f32_16x16x32_bf16(wah, vl, acc[dt], 0, 0, 0);
      acc[dt] = __builtin_amdgcn_mfma_f32_16x16x32_bf16(wal, vh, acc[dt], 0, 0, 0);
    }
  }

  // ---- full-width cross-wave reduce (1 barrier) + writes ----
#pragma unroll
  for (int dt = 0; dt < 4; ++dt)
#pragma unroll
    for (int i = 0; i < 4; ++i)
      red[w][l4 * 4 + i][dt * 16 + l16] = acc[dt][i];
  __syncthreads();
  for (int e = t; e < 16 * HD; e += 512) {
    const int row = e >> 6, d = e & 63;
    float sum = 0.f;
#pragma unroll
    for (int ww = 0; ww < 8; ++ww) sum += red[ww][row][d];
    const int sgr = s0 + row;
    unsigned short hb = bf16_rne(sum);
    unsigned short lb = bf16_rne(sum - bf16_f(hb));
    const size_t rw = ((size_t)((bh >> 4) * S + sgr)) * DIM + h * HD + d;
    swhi[rw] = hb;
    swlo[rw] = lb;
    const size_t oi = ((size_t)bh * S + sgr) * HD + d;
    ohi[oi] = hb;
    olo[oi] = lb;
  }
}

// ----------------------------------------------------------- layernorm ----
__global__ __launch_bounds__(256) void k_layernorm(float* __restrict__ out,
                                                   const float* __restrict__ gamma,
                                                   const float* __restrict__ beta) {
  const int W = 2 * DIM;
  const int r = blockIdx.x;
  float* row = out + (size_t)r * W;
  const int t = threadIdx.x;
  float4 vals[2];
  float sum = 0.f, sq = 0.f;
#pragma unroll
  for (int i = 0; i < 2; ++i) {
    float4 v = *(const float4*)(row + (i * 256 + t) * 4);
    vals[i] = v;
    sum += v.x + v.y + v.z + v.w;
    sq += v.x * v.x + v.y * v.y + v.z * v.z + v.w * v.w;
  }
#pragma unroll
  for (int off = 32; off >= 1; off >>= 1) {
    sum += __shfl_xor(sum, off, 64);
    sq  += __shfl_xor(sq,  off, 64);
  }
  __shared__ float rs[4], rq[4];
  const int wave = t >> 6, lane = t & 63;
  if (lane == 0) { rs[wave] = sum; rq[wave] = sq; }
  __syncthreads();
  sum = rs[0] + rs[1] + rs[2] + rs[3];
  sq  = rq[0] + rq[1] + rq[2] + rq[3];
  const float mean = sum / W;
  const float var = sq / W - mean * mean;
  const float rstd = rsqrtf(var + 1e-5f);
#pragma unroll
  for (int i = 0; i < 2; ++i) {
    int base = (i * 256 + t) * 4;
    float4 v = vals[i];
    float4 g = *(const float4*)(gamma + base);
    float4 bb = *(const float4*)(beta + base);
    v.x = (v.x - mean) * rstd * g.x + bb.x;
    v.y = (v.y - mean) * rstd * g.y + bb.y;
    v.z = (v.z - mean) * rstd * g.z + bb.z;
    v.w = (v.w - mean) * rstd * g.w + bb.w;
    *(float4*)(row + base) = v;
  }
}

// ---------------------------------------------------------------- launch --
extern "C" void kernel_launch(void* const* d_in, const int* in_sizes, int n_in,
                              void* d_out, int out_size, void* d_ws, size_t ws_size,
                              hipStream_t stream) {
  const float* zr       = (const float*)d_in[0];
  const float* zi       = (const float*)d_in[1];
  const float* stored   = (const float*)d_in[3];
  const float* Wq       = (const float*)d_in[4];
  const float* Wk       = (const float*)d_in[5];
  const float* Wv       = (const float*)d_in[6];
  const float* Wo       = (const float*)d_in[7];
  const float* bo       = (const float*)d_in[8];
  const float* log_temp = (const float*)d_in[9];
  const float* gamma    = (const float*)d_in[10];
  const float* beta     = (const float*)d_in[11];
  float* out = (float*)d_out;

  // --- workspace layout, 64 MB peak with lifetime overlays ---
  char* base = (char*)d_ws;
  unsigned short* vthi = (unsigned short*)(base + (size_t)0);     // 0-6
  unsigned short* vtlo = (unsigned short*)(base + (6u << 20));    // 6-12
  unsigned short* phi  = (unsigned short*)(base + (12u << 20));   // 12-18
  unsigned short* plo  = (unsigned short*)(base + (18u << 20));   // 18-24
  unsigned short* swhi = (unsigned short*)(base + (12u << 20));   // 12-16 (over dead phi/plo)
  unsigned short* swlo = (unsigned short*)(base + (16u << 20));   // 16-20
  unsigned short* wqh  = (unsigned short*)(base + (24u << 20));   // 24-26
  unsigned short* wql  = (unsigned short*)(base + (26u << 20));   // 26-28
  unsigned short* wkh  = (unsigned short*)(base + (28u << 20));   // 28-30
  unsigned short* wkl  = (unsigned short*)(base + (30u << 20));   // 30-32
  unsigned short* wvh  = (unsigned short*)(base + (32u << 20));   // 32-34
  unsigned short* wvl  = (unsigned short*)(base + (34u << 20));   // 34-36
  unsigned short* woh  = (unsigned short*)(base + (24u << 20));   // 24-28 (over dead wq/wk)
  unsigned short* wol  = (unsigned short*)(base + (28u << 20));   // 28-32
  float* mag = (float*)(base + (36u << 20));                      // 36-44
  unsigned short* qhi = (unsigned short*)(base + (36u << 20));    // 36-40 (over dead mag)
  unsigned short* qlo = (unsigned short*)(base + (40u << 20));    // 40-44
  unsigned short* s1hi = (unsigned short*)(base + (44u << 20));   // 44-48
  unsigned short* s1lo = (unsigned short*)(base + (48u << 20));   // 48-52
  unsigned short* khi  = (unsigned short*)(base + (52u << 20));   // 52-58
  unsigned short* klo  = (unsigned short*)(base + (58u << 20));   // 58-64

  const int n4 = B * S * DIM / 4;            // 524288
  k_mag<<<(n4 + 255) / 256, 256, 0, stream>>>(zr, zi, mag, n4);
  const int p4 = B * PT * DIM / 4;           // 786432
  // pattern build + hi/lo split fused
  k_patt_split<<<(p4 + 255) / 256, 256, 0, stream>>>(stored, mag, phi, plo, p4);

  const int w4 = DIM * DIM / 4;              // 262144
  k_split_plain<<<w4 / 256, 256, 0, stream>>>(Wq, wqh, wql, w4);
  k_split_plain<<<w4 / 256, 256, 0, stream>>>(Wk, wkh, wkl, w4);
  k_split_plain<<<w4 / 256, 256, 0, stream>>>(Wv, wvh, wvl, w4);

  // Q = mag @ Wq^T  (A rows remapped into patt), head-major hi/lo out
  dim3 gq(1024 / 128, 2048 / 128);
  k_gemm_mfma<<<gq, 256, 0, stream>>>(phi, plo, wqh, wql, nullptr, nullptr,
                                      qhi, qlo, 2048, 1024, 1024, 1, 1024, 1);
  // K = patt @ Wk^T, head-major hi/lo out
  dim3 gkv(1024 / 128, 3072 / 128);
  k_gemm_mfma<<<gkv, 256, 0, stream>>>(phi, plo, wkh, wkl, nullptr, nullptr,
                                       khi, klo, 3072, 1024, 1024, 1, 1536, 0);
  // V = patt @ Wv^T, V^T hi/lo out
  k_gemm_mfma<<<gkv, 256, 0, stream>>>(phi, plo, wvh, wvl, nullptr, nullptr,
                                       vthi, vtlo, 3072, 1024, 1024, 2, 1536, 0);

  // Wo split (after wq/wk dead)
  const int wo4 = 2 * DIM * DIM / 4;         // 524288
  k_split_plain<<<wo4 / 256, 256, 0, stream>>>(Wo, woh, wol, wo4);

  const int ablocks = B * H * (S / 16);      // 2048
  k_attn_mfma<<<ablocks, 512, 0, stream>>>(qhi, qlo, khi, klo, vthi, vtlo,
                                           log_temp, swhi, swlo, s1hi, s1lo);
  k_attn_mfma<<<ablocks, 512, 0, stream>>>(s1hi, s1lo, khi, klo, vthi, vtlo,
                                           log_temp, swhi, swlo, qhi, qlo);
  k_attn_mfma<<<ablocks, 512, 0, stream>>>(qhi, qlo, khi, klo, vthi, vtlo,
                                           log_temp, swhi, swlo, s1hi, s1lo);

  // out = sw @ Wo^T + bo, fp32
  dim3 go(2048 / 128, 2048 / 128);
  k_gemm_mfma<<<go, 256, 0, stream>>>(swhi, swlo, woh, wol, bo, out,
                                      nullptr, nullptr, 2048, 2048, 1024, 0, 0, 0);
  k_layernorm<<<B * S, 256, 0, stream>>>(out, gamma, beta);
}

// Round 15
// 633.675 us; speedup vs baseline: 1.2642x; 1.2642x over previous
//
#include <hip/hip_runtime.h>
#include <math.h>

#define DIM 1024
#define P0 512
#define H 16
#define HD 64
#define B 2
#define S 1024
#define PT 1536   // P0 + S

typedef __attribute__((ext_vector_type(8))) short short8v;    // bf16 MFMA frag
typedef __attribute__((ext_vector_type(4))) float f32x4;
typedef __attribute__((ext_vector_type(8))) unsigned short ushort8v;
typedef __attribute__((ext_vector_type(4))) unsigned short ushort4v;
typedef unsigned long long ull;
struct ull2 { ull a, b; };   // 16B carrier for short8v bit_cast

__device__ __forceinline__ unsigned short bf16_rne(float x) {
  unsigned u = __builtin_bit_cast(unsigned, x);
  u += 0x7FFFu + ((u >> 16) & 1u);
  return (unsigned short)(u >> 16);
}
__device__ __forceinline__ float bf16_f(unsigned short h) {
  unsigned u = ((unsigned)h) << 16;
  return __builtin_bit_cast(float, u);
}

// ---------------------------------------------------------------- mag ----
__global__ __launch_bounds__(256) void k_mag(const float* __restrict__ zr,
                                             const float* __restrict__ zi,
                                             float* __restrict__ mag, int n4) {
  int i = blockIdx.x * blockDim.x + threadIdx.x;
  if (i < n4) {
    float4 a = ((const float4*)zr)[i];
    float4 b = ((const float4*)zi)[i];
    float4 o;
    o.x = sqrtf(a.x * a.x + b.x * b.x);
    o.y = sqrtf(a.y * a.y + b.y * b.y);
    o.z = sqrtf(a.z * a.z + b.z * b.z);
    o.w = sqrtf(a.w * a.w + b.w * b.w);
    ((float4*)mag)[i] = o;
  }
}

// -------------------------------- pattern + hi/lo split (fused) ----------
__global__ __launch_bounds__(256) void k_patt_split(const float* __restrict__ stored,
                                                    const float* __restrict__ mag,
                                                    unsigned short* __restrict__ phi,
                                                    unsigned short* __restrict__ plo,
                                                    int n4) {
  int i = blockIdx.x * blockDim.x + threadIdx.x;
  if (i >= n4) return;
  int d4 = i & (DIM / 4 - 1);
  int p  = (i >> 8) % PT;
  int b  = i / (PT * (DIM / 4));
  float4 v;
  if (p < P0) {
    v = ((const float4*)stored)[(size_t)p * (DIM / 4) + d4];
  } else {
    v = ((const float4*)mag)[((size_t)(b * S + (p - P0))) * (DIM / 4) + d4];
  }
  float xs[4] = {v.x, v.y, v.z, v.w};
  ushort4v hv, lv;
#pragma unroll
  for (int j = 0; j < 4; ++j) {
    unsigned short hb = bf16_rne(xs[j]);
    hv[j] = hb;
    lv[j] = bf16_rne(xs[j] - bf16_f(hb));
  }
  ((ushort4v*)phi)[(size_t)i] = hv;
  ((ushort4v*)plo)[(size_t)i] = lv;
}

// ---------------------------------------------- plain hi/lo bf16 split ----
__global__ __launch_bounds__(256) void k_split_plain(const float* __restrict__ X,
                                                     unsigned short* __restrict__ hi,
                                                     unsigned short* __restrict__ lo,
                                                     int n4) {
  int i = blockIdx.x * 256 + threadIdx.x;
  if (i >= n4) return;
  float4 v = ((const float4*)X)[(size_t)i];
  float xs[4] = {v.x, v.y, v.z, v.w};
  ushort4v hv, lv;
#pragma unroll
  for (int j = 0; j < 4; ++j) {
    unsigned short hb = bf16_rne(xs[j]);
    hv[j] = hb;
    lv[j] = bf16_rne(xs[j] - bf16_f(hb));
  }
  ((ushort4v*)hi)[(size_t)i] = hv;
  ((ushort4v*)lo)[(size_t)i] = lv;
}

// ------------------------------------------------------- MFMA GEMM --------
// C(M,N) = A @ W^T with A,W pre-split hi/lo bf16 row-major (K-contig).
// 128x128 tile, BK=32, 256 threads = 4 waves (2x2), 3-product split.
__global__ __launch_bounds__(256, 2) void k_gemm_mfma(
    const unsigned short* __restrict__ Ah, const unsigned short* __restrict__ Al,
    const unsigned short* __restrict__ Wh, const unsigned short* __restrict__ Wl,
    const float* __restrict__ bias, float* __restrict__ Cf,
    unsigned short* __restrict__ Ohi, unsigned short* __restrict__ Olo,
    int M, int N, int K, int mode, int rpb, int aremap) {
  __shared__ short8v lds[4][4 * 132];   // Ah, Al, Wh, Wl frag-major tiles
  const int t = threadIdx.x;
  const int w = t >> 6, lane = t & 63;
  const int l16 = lane & 15, l4 = lane >> 4;
  const int wr = w >> 1, wc = w & 1;
  const int bm = blockIdx.y, bn = blockIdx.x;

  f32x4 acc[4][4];
#pragma unroll
  for (int mi = 0; mi < 4; ++mi)
#pragma unroll
    for (int nj = 0; nj < 4; ++nj) acc[mi][nj] = (f32x4){0.f, 0.f, 0.f, 0.f};

  for (int k0 = 0; k0 < K; k0 += 32) {
    __syncthreads();
#pragma unroll
    for (int rep = 0; rep < 2; ++rep) {
      int u = rep * 256 + t;
      int kb = u & 3, r = u >> 2;
      int agr = bm * 128 + r;
      int ar = aremap ? (agr + 512 + ((agr >> 10) << 9)) : agr;
      size_t ga = (size_t)ar * K + k0 + kb * 8;
      size_t gw = (size_t)(bn * 128 + r) * K + k0 + kb * 8;
      int li = kb * 132 + r;
      lds[0][li] = *(const short8v*)(Ah + ga);
      lds[1][li] = *(const short8v*)(Al + ga);
      lds[2][li] = *(const short8v*)(Wh + gw);
      lds[3][li] = *(const short8v*)(Wl + gw);
    }
    __syncthreads();
    short8v af[4][2], bf[4][2];
#pragma unroll
    for (int mi = 0; mi < 4; ++mi) {
      int li = l4 * 132 + wr * 64 + mi * 16 + l16;
      af[mi][0] = lds[0][li];
      af[mi][1] = lds[1][li];
    }
#pragma unroll
    for (int nj = 0; nj < 4; ++nj) {
      int li = l4 * 132 + wc * 64 + nj * 16 + l16;
      bf[nj][0] = lds[2][li];
      bf[nj][1] = lds[3][li];
    }
#pragma unroll
    for (int mi = 0; mi < 4; ++mi)
#pragma unroll
      for (int nj = 0; nj < 4; ++nj) {
        acc[mi][nj] = __builtin_amdgcn_mfma_f32_16x16x32_bf16(af[mi][0], bf[nj][0], acc[mi][nj], 0, 0, 0);
        acc[mi][nj] = __builtin_amdgcn_mfma_f32_16x16x32_bf16(af[mi][0], bf[nj][1], acc[mi][nj], 0, 0, 0);
        acc[mi][nj] = __builtin_amdgcn_mfma_f32_16x16x32_bf16(af[mi][1], bf[nj][0], acc[mi][nj], 0, 0, 0);
      }
  }

#pragma unroll
  for (int mi = 0; mi < 4; ++mi)
#pragma unroll
    for (int nj = 0; nj < 4; ++nj)
#pragma unroll
      for (int i = 0; i < 4; ++i) {
        int rg = bm * 128 + wr * 64 + mi * 16 + l4 * 4 + i;
        int c  = bn * 128 + wc * 64 + nj * 16 + l16;
        float v = acc[mi][nj][i];
        if (mode == 0) {
          Cf[(size_t)rg * N + c] = v + (bias ? bias[c] : 0.f);
        } else {
          int b = rg >= rpb ? 1 : 0;
          int p = rg - b * rpb;
          int hh = c >> 6, d = c & 63;
          size_t o = (mode == 1)
                         ? ((((size_t)(b * 16 + hh)) * rpb + p) * 64 + d)
                         : ((((size_t)(b * 16 + hh)) * 64 + d) * (size_t)rpb + p);
          unsigned short hb = bf16_rne(v);
          Ohi[o] = hb;
          Olo[o] = bf16_rne(v - bf16_f(hb));
        }
      }
}

// ------------------------------------------------- MFMA attention step ----
// One Hopfield iteration. Block = 16 query rows of one (b,h), 8 waves.
// Round-13 structure (the measured best: skip-work > straight-line; round
// 14's branch-free variant regressed 178->208 us). Swapped QK^T; interleaved
// tile ownership + causal tile-skip; sparsemax = 1 max + 7 Michelot from
// tau0=gmax-1 (exact); shfl-PV; full-width 1-barrier reduce. NEW: PV pairs
// whose 256 weights are ALL zero (post-sparsemax sparsity) are skipped via
// a single __any(pm > tau) test — subsumes the causal skip, output
// bitwise-identical (skipped tiles would contribute exact zeros).
// __launch_bounds__(512,4): HARD (rounds 6 & 10 spilled under tighter
// caps). Spill sentinel: WRITE_SIZE must stay ~16 MB/dispatch.
__global__ __launch_bounds__(512, 4) void k_attn_mfma(
    const unsigned short* __restrict__ shi, const unsigned short* __restrict__ slo,
    const unsigned short* __restrict__ khi, const unsigned short* __restrict__ klo,
    const unsigned short* __restrict__ vthi, const unsigned short* __restrict__ vtlo,
    const float* __restrict__ log_temp,
    unsigned short* __restrict__ swhi, unsigned short* __restrict__ swlo,
    unsigned short* __restrict__ ohi, unsigned short* __restrict__ olo) {
  __shared__ float part[8][2][2][20];             // 5120 B reduction scratch
  __shared__ float red[8][16][68];                // 34816 B full-width reduce
  const int t = threadIdx.x;
  const int w = t >> 6, lane = t & 63;
  const int l16 = lane & 15, l4 = lane >> 4;
  // XCD-aware bijective swizzle (2048 % 8 == 0)
  const int bid = blockIdx.x;
  const int tile = (bid & 7) * 256 + (bid >> 3);
  const int stile = tile & 63;
  const int bh = tile >> 6;
  const int h = bh & 15;
  const int s0 = stile * 16;
  const int maxTile = stile + 33;   // tile pt active iff pt <= maxTile

  float lt = log_temp[h];
  lt = fminf(fmaxf(lt, -4.f), 4.f);
  const float inv_scale = 1.f / (8.f * expf(lt));

  // state B-fragments (swapped mfma): col = l16 = query row, k = 8*l4+j
  const size_t arow = ((size_t)bh * S + s0 + l16) * HD + 8 * l4;
  short8v ahi0 = *(const short8v*)(shi + arow);
  short8v ahi1 = *(const short8v*)(shi + arow + 32);
  short8v alo0 = *(const short8v*)(slo + arow);
  short8v alo1 = *(const short8v*)(slo + arow + 32);

  const size_t kb = (size_t)bh * PT * HD;
  const size_t vb = (size_t)bh * HD * PT;
  const int sg = s0 + l16;

  // ---- QK^T (swapped, interleaved tiles, causal tile-skip) ----
  float z0[6][4], z1[6][4];
#pragma unroll
  for (int j = 0; j < 6; ++j) {
    const int tA = w + 16 * j, tB = tA + 8;
    if (tA > maxTile) {          // whole pair fully masked (wave-uniform)
#pragma unroll
      for (int i = 0; i < 4; ++i) { z0[j][i] = -1e9f; z1[j][i] = -1e9f; }
    } else {
      const size_t k0 = kb + ((size_t)(tA * 16 + l16)) * HD + 8 * l4;
      f32x4 a0 = {0.f, 0.f, 0.f, 0.f};
      {
        short8v b00 = *(const short8v*)(khi + k0);
        short8v b01 = *(const short8v*)(khi + k0 + 32);
        short8v c00 = *(const short8v*)(klo + k0);
        short8v c01 = *(const short8v*)(klo + k0 + 32);
        a0 = __builtin_amdgcn_mfma_f32_16x16x32_bf16(b00, ahi0, a0, 0, 0, 0);
        a0 = __builtin_amdgcn_mfma_f32_16x16x32_bf16(b01, ahi1, a0, 0, 0, 0);
        a0 = __builtin_amdgcn_mfma_f32_16x16x32_bf16(b00, alo0, a0, 0, 0, 0);
        a0 = __builtin_amdgcn_mfma_f32_16x16x32_bf16(b01, alo1, a0, 0, 0, 0);
        a0 = __builtin_amdgcn_mfma_f32_16x16x32_bf16(c00, ahi0, a0, 0, 0, 0);
        a0 = __builtin_amdgcn_mfma_f32_16x16x32_bf16(c01, ahi1, a0, 0, 0, 0);
      }
#pragma unroll
      for (int i = 0; i < 4; ++i) {
        const int pA = tA * 16 + l4 * 4 + i;
        z0[j][i] = (pA > P0 + sg) ? -1e9f : a0[i] * inv_scale;
      }
      if (tB <= maxTile) {
        const size_t k1 = kb + ((size_t)(tB * 16 + l16)) * HD + 8 * l4;
        f32x4 a1 = {0.f, 0.f, 0.f, 0.f};
        short8v b10 = *(const short8v*)(khi + k1);
        short8v b11 = *(const short8v*)(khi + k1 + 32);
        short8v c10 = *(const short8v*)(klo + k1);
        short8v c11 = *(const short8v*)(klo + k1 + 32);
        a1 = __builtin_amdgcn_mfma_f32_16x16x32_bf16(b10, ahi0, a1, 0, 0, 0);
        a1 = __builtin_amdgcn_mfma_f32_16x16x32_bf16(b11, ahi1, a1, 0, 0, 0);
        a1 = __builtin_amdgcn_mfma_f32_16x16x32_bf16(b10, alo0, a1, 0, 0, 0);
        a1 = __builtin_amdgcn_mfma_f32_16x16x32_bf16(b11, alo1, a1, 0, 0, 0);
        a1 = __builtin_amdgcn_mfma_f32_16x16x32_bf16(c10, ahi0, a1, 0, 0, 0);
        a1 = __builtin_amdgcn_mfma_f32_16x16x32_bf16(c11, ahi1, a1, 0, 0, 0);
#pragma unroll
        for (int i = 0; i < 4; ++i) {
          const int pB = tB * 16 + l4 * 4 + i;
          z1[j][i] = (pB > P0 + sg) ? -1e9f : a1[i] * inv_scale;
        }
      } else {
#pragma unroll
        for (int i = 0; i < 4; ++i) z1[j][i] = -1e9f;
      }
    }
  }

  // ---- row max (scalar per lane; dual chains) ----
  float mA = -1e30f, mB = -1e30f;
#pragma unroll
  for (int j = 0; j < 6; ++j) {
    if (w + 16 * j <= maxTile) {
#pragma unroll
      for (int i = 0; i < 4; ++i) {
        mA = fmaxf(mA, z0[j][i]);
        mB = fmaxf(mB, z1[j][i]);
      }
    }
  }
  float mxv = fmaxf(mA, mB);
  mxv = fmaxf(mxv, __shfl_xor(mxv, 16, 64));
  mxv = fmaxf(mxv, __shfl_xor(mxv, 32, 64));
  if (lane < 16) part[w][0][0][lane] = mxv;
  __syncthreads();
  float gm = -1e30f;
#pragma unroll
  for (int ww = 0; ww < 8; ++ww) gm = fmaxf(gm, part[ww][0][0][l16]);

  // ---- Michelot from tau0 = gmax-1: 7 rounds, dual-chain scans ----
  float tau = gm - 1.f;
  for (int it = 0; it < 7; ++it) {
    const int sl = (it + 1) & 1;
    float ca = 0.f, cb = 0.f, sa = 0.f, sb = 0.f;
#pragma unroll
    for (int j = 0; j < 6; ++j) {
      if (w + 16 * j <= maxTile) {
#pragma unroll
        for (int i = 0; i < 4; ++i) {
          float a = z0[j][i];
          if (a > tau) { ca += 1.f; sa += a; }
          float b2 = z1[j][i];
          if (b2 > tau) { cb += 1.f; sb += b2; }
        }
      }
    }
    float c = ca + cb, s = sa + sb;
    c += __shfl_xor(c, 16, 64);
    c += __shfl_xor(c, 32, 64);
    s += __shfl_xor(s, 16, 64);
    s += __shfl_xor(s, 32, 64);
    if (lane < 16) {
      part[w][sl][0][lane] = c;
      part[w][sl][1][lane] = s;
    }
    __syncthreads();
    float rc = 0.f, rs = 0.f;
#pragma unroll
    for (int ww = 0; ww < 8; ++ww) {
      rc += part[ww][sl][0][l16];
      rs += part[ww][sl][1][l16];
    }
    tau = (rs - 1.f) / rc;
  }

  // ---- PV: sparsity-skip + in-register weight exchange + 3-prod MFMA ----
  f32x4 acc[4];
#pragma unroll
  for (int dt = 0; dt < 4; ++dt) acc[dt] = (f32x4){0.f, 0.f, 0.f, 0.f};
#pragma unroll
  for (int kk = 0; kk < 6; ++kk) {
    const int tA = w + 16 * kk, tB = tA + 8;
    // per-lane max of this pair's 8 scores; if NO lane beats tau, all
    // 256 weights of both tiles are zero -> pair contributes nothing.
    float pm = fmaxf(fmaxf(fmaxf(z0[kk][0], z0[kk][1]),
                           fmaxf(z0[kk][2], z0[kk][3])),
                     fmaxf(fmaxf(z1[kk][0], z1[kk][1]),
                           fmaxf(z1[kk][2], z1[kk][3])));
    if (!__any(pm > tau)) continue;   // wave-uniform; subsumes causal skip
    ushort4v h0v, l0v, h1v, l1v;
#pragma unroll
    for (int i = 0; i < 4; ++i) {
      float w0 = fmaxf(z0[kk][i] - tau, 0.f);
      float w1 = fmaxf(z1[kk][i] - tau, 0.f);
      unsigned short hb0 = bf16_rne(w0);
      unsigned short hb1 = bf16_rne(w1);
      h0v[i] = hb0; l0v[i] = bf16_rne(w0 - bf16_f(hb0));
      h1v[i] = hb1; l1v[i] = bf16_rne(w1 - bf16_f(hb1));
    }
    const ull P0v = __builtin_bit_cast(ull, h0v);
    const ull P1v = __builtin_bit_cast(ull, h1v);
    const ull Q0v = __builtin_bit_cast(ull, l0v);
    const ull Q1v = __builtin_bit_cast(ull, l1v);
    const int srcA = l16 + 16 * (2 * (l4 & 1));
    const int srcB = srcA + 16;
    ull a0 = __shfl(P0v, srcA, 64);
    ull a1 = __shfl(P1v, srcA, 64);
    ull b0 = __shfl(P0v, srcB, 64);
    ull b1 = __shfl(P1v, srcB, 64);
    ull qa0 = __shfl(Q0v, srcA, 64);
    ull qa1 = __shfl(Q1v, srcA, 64);
    ull qb0 = __shfl(Q0v, srcB, 64);
    ull qb1 = __shfl(Q1v, srcB, 64);
    ull2 th = { (l4 < 2) ? a0 : a1, (l4 < 2) ? b0 : b1 };
    ull2 tl = { (l4 < 2) ? qa0 : qa1, (l4 < 2) ? qb0 : qb1 };
    short8v wah = __builtin_bit_cast(short8v, th);
    short8v wal = __builtin_bit_cast(short8v, tl);
    // permuted k-order: lanes l4<2 read tile A's p-range, l4>=2 tile B's
    const int pbase = (l4 < 2) ? (tA * 16 + 8 * l4) : (tB * 16 + 8 * (l4 - 2));
#pragma unroll
    for (int dt = 0; dt < 4; ++dt) {
      const size_t vo = vb + (size_t)(dt * 16 + l16) * PT + pbase;
      short8v vh = *(const short8v*)(vthi + vo);
      short8v vl = *(const short8v*)(vtlo + vo);
      acc[dt] = __builtin_amdgcn_mfma_f32_16x16x32_bf16(wah, vh, acc[dt], 0, 0, 0);
      acc[dt] = __builtin_amdgcn_mfma_f32_16x16x32_bf16(wah, vl, acc[dt], 0, 0, 0);
      acc[dt] = __builtin_amdgcn_mfma_f32_16x16x32_bf16(wal, vh, acc[dt], 0, 0, 0);
    }
  }

  // ---- full-width cross-wave reduce (1 barrier) + writes ----
#pragma unroll
  for (int dt = 0; dt < 4; ++dt)
#pragma unroll
    for (int i = 0; i < 4; ++i)
      red[w][l4 * 4 + i][dt * 16 + l16] = acc[dt][i];
  __syncthreads();
  for (int e = t; e < 16 * HD; e += 512) {
    const int row = e >> 6, d = e & 63;
    float sum = 0.f;
#pragma unroll
    for (int ww = 0; ww < 8; ++ww) sum += red[ww][row][d];
    const int sgr = s0 + row;
    unsigned short hb = bf16_rne(sum);
    unsigned short lb = bf16_rne(sum - bf16_f(hb));
    const size_t rw = ((size_t)((bh >> 4) * S + sgr)) * DIM + h * HD + d;
    swhi[rw] = hb;
    swlo[rw] = lb;
    const size_t oi = ((size_t)bh * S + sgr) * HD + d;
    ohi[oi] = hb;
    olo[oi] = lb;
  }
}

// ----------------------------------------------------------- layernorm ----
__global__ __launch_bounds__(256) void k_layernorm(float* __restrict__ out,
                                                   const float* __restrict__ gamma,
                                                   const float* __restrict__ beta) {
  const int W = 2 * DIM;
  const int r = blockIdx.x;
  float* row = out + (size_t)r * W;
  const int t = threadIdx.x;
  float4 vals[2];
  float sum = 0.f, sq = 0.f;
#pragma unroll
  for (int i = 0; i < 2; ++i) {
    float4 v = *(const float4*)(row + (i * 256 + t) * 4);
    vals[i] = v;
    sum += v.x + v.y + v.z + v.w;
    sq += v.x * v.x + v.y * v.y + v.z * v.z + v.w * v.w;
  }
#pragma unroll
  for (int off = 32; off >= 1; off >>= 1) {
    sum += __shfl_xor(sum, off, 64);
    sq  += __shfl_xor(sq,  off, 64);
  }
  __shared__ float rs[4], rq[4];
  const int wave = t >> 6, lane = t & 63;
  if (lane == 0) { rs[wave] = sum; rq[wave] = sq; }
  __syncthreads();
  sum = rs[0] + rs[1] + rs[2] + rs[3];
  sq  = rq[0] + rq[1] + rq[2] + rq[3];
  const float mean = sum / W;
  const float var = sq / W - mean * mean;
  const float rstd = rsqrtf(var + 1e-5f);
#pragma unroll
  for (int i = 0; i < 2; ++i) {
    int base = (i * 256 + t) * 4;
    float4 v = vals[i];
    float4 g = *(const float4*)(gamma + base);
    float4 bb = *(const float4*)(beta + base);
    v.x = (v.x - mean) * rstd * g.x + bb.x;
    v.y = (v.y - mean) * rstd * g.y + bb.y;
    v.z = (v.z - mean) * rstd * g.z + bb.z;
    v.w = (v.w - mean) * rstd * g.w + bb.w;
    *(float4*)(row + base) = v;
  }
}

// ---------------------------------------------------------------- launch --
extern "C" void kernel_launch(void* const* d_in, const int* in_sizes, int n_in,
                              void* d_out, int out_size, void* d_ws, size_t ws_size,
                              hipStream_t stream) {
  const float* zr       = (const float*)d_in[0];
  const float* zi       = (const float*)d_in[1];
  const float* stored   = (const float*)d_in[3];
  const float* Wq       = (const float*)d_in[4];
  const float* Wk       = (const float*)d_in[5];
  const float* Wv       = (const float*)d_in[6];
  const float* Wo       = (const float*)d_in[7];
  const float* bo       = (const float*)d_in[8];
  const float* log_temp = (const float*)d_in[9];
  const float* gamma    = (const float*)d_in[10];
  const float* beta     = (const float*)d_in[11];
  float* out = (float*)d_out;

  // --- workspace layout, 64 MB peak with lifetime overlays ---
  char* base = (char*)d_ws;
  unsigned short* vthi = (unsigned short*)(base + (size_t)0);     // 0-6
  unsigned short* vtlo = (unsigned short*)(base + (6u << 20));    // 6-12
  unsigned short* phi  = (unsigned short*)(base + (12u << 20));   // 12-18
  unsigned short* plo  = (unsigned short*)(base + (18u << 20));   // 18-24
  unsigned short* swhi = (unsigned short*)(base + (12u << 20));   // 12-16 (over dead phi/plo)
  unsigned short* swlo = (unsigned short*)(base + (16u << 20));   // 16-20
  unsigned short* wqh  = (unsigned short*)(base + (24u << 20));   // 24-26
  unsigned short* wql  = (unsigned short*)(base + (26u << 20));   // 26-28
  unsigned short* wkh  = (unsigned short*)(base + (28u << 20));   // 28-30
  unsigned short* wkl  = (unsigned short*)(base + (30u << 20));   // 30-32
  unsigned short* wvh  = (unsigned short*)(base + (32u << 20));   // 32-34
  unsigned short* wvl  = (unsigned short*)(base + (34u << 20));   // 34-36
  unsigned short* woh  = (unsigned short*)(base + (24u << 20));   // 24-28 (over dead wq/wk)
  unsigned short* wol  = (unsigned short*)(base + (28u << 20));   // 28-32
  float* mag = (float*)(base + (36u << 20));                      // 36-44
  unsigned short* qhi = (unsigned short*)(base + (36u << 20));    // 36-40 (over dead mag)
  unsigned short* qlo = (unsigned short*)(base + (40u << 20));    // 40-44
  unsigned short* s1hi = (unsigned short*)(base + (44u << 20));   // 44-48
  unsigned short* s1lo = (unsigned short*)(base + (48u << 20));   // 48-52
  unsigned short* khi  = (unsigned short*)(base + (52u << 20));   // 52-58
  unsigned short* klo  = (unsigned short*)(base + (58u << 20));   // 58-64

  const int n4 = B * S * DIM / 4;            // 524288
  k_mag<<<(n4 + 255) / 256, 256, 0, stream>>>(zr, zi, mag, n4);
  const int p4 = B * PT * DIM / 4;           // 786432
  // pattern build + hi/lo split fused
  k_patt_split<<<(p4 + 255) / 256, 256, 0, stream>>>(stored, mag, phi, plo, p4);

  const int w4 = DIM * DIM / 4;              // 262144
  k_split_plain<<<w4 / 256, 256, 0, stream>>>(Wq, wqh, wql, w4);
  k_split_plain<<<w4 / 256, 256, 0, stream>>>(Wk, wkh, wkl, w4);
  k_split_plain<<<w4 / 256, 256, 0, stream>>>(Wv, wvh, wvl, w4);

  // Q = mag @ Wq^T  (A rows remapped into patt), head-major hi/lo out
  dim3 gq(1024 / 128, 2048 / 128);
  k_gemm_mfma<<<gq, 256, 0, stream>>>(phi, plo, wqh, wql, nullptr, nullptr,
                                      qhi, qlo, 2048, 1024, 1024, 1, 1024, 1);
  // K = patt @ Wk^T, head-major hi/lo out
  dim3 gkv(1024 / 128, 3072 / 128);
  k_gemm_mfma<<<gkv, 256, 0, stream>>>(phi, plo, wkh, wkl, nullptr, nullptr,
                                       khi, klo, 3072, 1024, 1024, 1, 1536, 0);
  // V = patt @ Wv^T, V^T hi/lo out
  k_gemm_mfma<<<gkv, 256, 0, stream>>>(phi, plo, wvh, wvl, nullptr, nullptr,
                                       vthi, vtlo, 3072, 1024, 1024, 2, 1536, 0);

  // Wo split (after wq/wk dead)
  const int wo4 = 2 * DIM * DIM / 4;         // 524288
  k_split_plain<<<wo4 / 256, 256, 0, stream>>>(Wo, woh, wol, wo4);

  const int ablocks = B * H * (S / 16);      // 2048
  k_attn_mfma<<<ablocks, 512, 0, stream>>>(qhi, qlo, khi, klo, vthi, vtlo,
                                           log_temp, swhi, swlo, s1hi, s1lo);
  k_attn_mfma<<<ablocks, 512, 0, stream>>>(s1hi, s1lo, khi, klo, vthi, vtlo,
                                           log_temp, swhi, swlo, qhi, qlo);
  k_attn_mfma<<<ablocks, 512, 0, stream>>>(qhi, qlo, khi, klo, vthi, vtlo,
                                           log_temp, swhi, swlo, s1hi, s1lo);

  // out = sw @ Wo^T + bo, fp32
  dim3 go(2048 / 128, 2048 / 128);
  k_gemm_mfma<<<go, 256, 0, stream>>>(swhi, swlo, woh, wol, bo, out,
                                      nullptr, nullptr, 2048, 2048, 1024, 0, 0, 0);
  k_layernorm<<<B * S, 256, 0, stream>>>(out, gamma, beta);
}

// Round 16
// 619.117 us; speedup vs baseline: 1.2939x; 1.0235x over previous
//
#include <hip/hip_runtime.h>
#include <math.h>

#define DIM 1024
#define P0 512
#define H 16
#define HD 64
#define B 2
#define S 1024
#define PT 1536   // P0 + S

typedef __attribute__((ext_vector_type(8))) short short8v;    // bf16 MFMA frag
typedef __attribute__((ext_vector_type(4))) float f32x4;
typedef __attribute__((ext_vector_type(8))) unsigned short ushort8v;
typedef __attribute__((ext_vector_type(4))) unsigned short ushort4v;
typedef unsigned long long ull;
struct ull2 { ull a, b; };   // 16B carrier for short8v bit_cast

__device__ __forceinline__ unsigned short bf16_rne(float x) {
  unsigned u = __builtin_bit_cast(unsigned, x);
  u += 0x7FFFu + ((u >> 16) & 1u);
  return (unsigned short)(u >> 16);
}
__device__ __forceinline__ float bf16_f(unsigned short h) {
  unsigned u = ((unsigned)h) << 16;
  return __builtin_bit_cast(float, u);
}

// ---------------------------------------------------------------- mag ----
__global__ __launch_bounds__(256) void k_mag(const float* __restrict__ zr,
                                             const float* __restrict__ zi,
                                             float* __restrict__ mag, int n4) {
  int i = blockIdx.x * blockDim.x + threadIdx.x;
  if (i < n4) {
    float4 a = ((const float4*)zr)[i];
    float4 b = ((const float4*)zi)[i];
    float4 o;
    o.x = sqrtf(a.x * a.x + b.x * b.x);
    o.y = sqrtf(a.y * a.y + b.y * b.y);
    o.z = sqrtf(a.z * a.z + b.z * b.z);
    o.w = sqrtf(a.w * a.w + b.w * b.w);
    ((float4*)mag)[i] = o;
  }
}

// -------------------------------- pattern + hi/lo split (fused) ----------
__global__ __launch_bounds__(256) void k_patt_split(const float* __restrict__ stored,
                                                    const float* __restrict__ mag,
                                                    unsigned short* __restrict__ phi,
                                                    unsigned short* __restrict__ plo,
                                                    int n4) {
  int i = blockIdx.x * blockDim.x + threadIdx.x;
  if (i >= n4) return;
  int d4 = i & (DIM / 4 - 1);
  int p  = (i >> 8) % PT;
  int b  = i / (PT * (DIM / 4));
  float4 v;
  if (p < P0) {
    v = ((const float4*)stored)[(size_t)p * (DIM / 4) + d4];
  } else {
    v = ((const float4*)mag)[((size_t)(b * S + (p - P0))) * (DIM / 4) + d4];
  }
  float xs[4] = {v.x, v.y, v.z, v.w};
  ushort4v hv, lv;
#pragma unroll
  for (int j = 0; j < 4; ++j) {
    unsigned short hb = bf16_rne(xs[j]);
    hv[j] = hb;
    lv[j] = bf16_rne(xs[j] - bf16_f(hb));
  }
  ((ushort4v*)phi)[(size_t)i] = hv;
  ((ushort4v*)plo)[(size_t)i] = lv;
}

// ---------------------------------------------- plain hi/lo bf16 split ----
__global__ __launch_bounds__(256) void k_split_plain(const float* __restrict__ X,
                                                     unsigned short* __restrict__ hi,
                                                     unsigned short* __restrict__ lo,
                                                     int n4) {
  int i = blockIdx.x * 256 + threadIdx.x;
  if (i >= n4) return;
  float4 v = ((const float4*)X)[(size_t)i];
  float xs[4] = {v.x, v.y, v.z, v.w};
  ushort4v hv, lv;
#pragma unroll
  for (int j = 0; j < 4; ++j) {
    unsigned short hb = bf16_rne(xs[j]);
    hv[j] = hb;
    lv[j] = bf16_rne(xs[j] - bf16_f(hb));
  }
  ((ushort4v*)hi)[(size_t)i] = hv;
  ((ushort4v*)lo)[(size_t)i] = lv;
}

// ------------------------------------------------------- MFMA GEMM --------
// C(M,N) = A @ W^T with A,W pre-split hi/lo bf16 row-major (K-contig).
// 128x128 tile, BK=32, 256 threads = 4 waves (2x2), 3-product split.
__global__ __launch_bounds__(256, 2) void k_gemm_mfma(
    const unsigned short* __restrict__ Ah, const unsigned short* __restrict__ Al,
    const unsigned short* __restrict__ Wh, const unsigned short* __restrict__ Wl,
    const float* __restrict__ bias, float* __restrict__ Cf,
    unsigned short* __restrict__ Ohi, unsigned short* __restrict__ Olo,
    int M, int N, int K, int mode, int rpb, int aremap) {
  __shared__ short8v lds[4][4 * 132];   // Ah, Al, Wh, Wl frag-major tiles
  const int t = threadIdx.x;
  const int w = t >> 6, lane = t & 63;
  const int l16 = lane & 15, l4 = lane >> 4;
  const int wr = w >> 1, wc = w & 1;
  const int bm = blockIdx.y, bn = blockIdx.x;

  f32x4 acc[4][4];
#pragma unroll
  for (int mi = 0; mi < 4; ++mi)
#pragma unroll
    for (int nj = 0; nj < 4; ++nj) acc[mi][nj] = (f32x4){0.f, 0.f, 0.f, 0.f};

  for (int k0 = 0; k0 < K; k0 += 32) {
    __syncthreads();
#pragma unroll
    for (int rep = 0; rep < 2; ++rep) {
      int u = rep * 256 + t;
      int kb = u & 3, r = u >> 2;
      int agr = bm * 128 + r;
      int ar = aremap ? (agr + 512 + ((agr >> 10) << 9)) : agr;
      size_t ga = (size_t)ar * K + k0 + kb * 8;
      size_t gw = (size_t)(bn * 128 + r) * K + k0 + kb * 8;
      int li = kb * 132 + r;
      lds[0][li] = *(const short8v*)(Ah + ga);
      lds[1][li] = *(const short8v*)(Al + ga);
      lds[2][li] = *(const short8v*)(Wh + gw);
      lds[3][li] = *(const short8v*)(Wl + gw);
    }
    __syncthreads();
    short8v af[4][2], bf[4][2];
#pragma unroll
    for (int mi = 0; mi < 4; ++mi) {
      int li = l4 * 132 + wr * 64 + mi * 16 + l16;
      af[mi][0] = lds[0][li];
      af[mi][1] = lds[1][li];
    }
#pragma unroll
    for (int nj = 0; nj < 4; ++nj) {
      int li = l4 * 132 + wc * 64 + nj * 16 + l16;
      bf[nj][0] = lds[2][li];
      bf[nj][1] = lds[3][li];
    }
#pragma unroll
    for (int mi = 0; mi < 4; ++mi)
#pragma unroll
      for (int nj = 0; nj < 4; ++nj) {
        acc[mi][nj] = __builtin_amdgcn_mfma_f32_16x16x32_bf16(af[mi][0], bf[nj][0], acc[mi][nj], 0, 0, 0);
        acc[mi][nj] = __builtin_amdgcn_mfma_f32_16x16x32_bf16(af[mi][0], bf[nj][1], acc[mi][nj], 0, 0, 0);
        acc[mi][nj] = __builtin_amdgcn_mfma_f32_16x16x32_bf16(af[mi][1], bf[nj][0], acc[mi][nj], 0, 0, 0);
      }
  }

#pragma unroll
  for (int mi = 0; mi < 4; ++mi)
#pragma unroll
    for (int nj = 0; nj < 4; ++nj)
#pragma unroll
      for (int i = 0; i < 4; ++i) {
        int rg = bm * 128 + wr * 64 + mi * 16 + l4 * 4 + i;
        int c  = bn * 128 + wc * 64 + nj * 16 + l16;
        float v = acc[mi][nj][i];
        if (mode == 0) {
          Cf[(size_t)rg * N + c] = v + (bias ? bias[c] : 0.f);
        } else {
          int b = rg >= rpb ? 1 : 0;
          int p = rg - b * rpb;
          int hh = c >> 6, d = c & 63;
          size_t o = (mode == 1)
                         ? ((((size_t)(b * 16 + hh)) * rpb + p) * 64 + d)
                         : ((((size_t)(b * 16 + hh)) * 64 + d) * (size_t)rpb + p);
          unsigned short hb = bf16_rne(v);
          Ohi[o] = hb;
          Olo[o] = bf16_rne(v - bf16_f(hb));
        }
      }
}

// ------------------------------------------------- MFMA attention step ----
// One Hopfield iteration. Block = 16 query rows of one (b,h), 8 waves.
// Round-15 structure + data-dependent SCAN skip: per-lane per-pair maxima
// pm[6] are computed once; Michelot's tau is monotone increasing from
// tau0=gmax-1, so a pair with pm<=tau can never contribute again — each
// scan round guards with __any(pm>tau) (subsumes the causal guard; skipped
// pairs would contribute exactly 0 -> tau sequence bitwise-identical).
// PV pair skip reuses pm. Sparsemax: 1 max + 7 Michelot (exact).
// __launch_bounds__(512,4): HARD (rounds 6 & 10 spilled under tighter
// caps). Spill sentinel: WRITE_SIZE must stay ~16 MB/dispatch.
__global__ __launch_bounds__(512, 4) void k_attn_mfma(
    const unsigned short* __restrict__ shi, const unsigned short* __restrict__ slo,
    const unsigned short* __restrict__ khi, const unsigned short* __restrict__ klo,
    const unsigned short* __restrict__ vthi, const unsigned short* __restrict__ vtlo,
    const float* __restrict__ log_temp,
    unsigned short* __restrict__ swhi, unsigned short* __restrict__ swlo,
    unsigned short* __restrict__ ohi, unsigned short* __restrict__ olo) {
  __shared__ float part[8][2][2][20];             // 5120 B reduction scratch
  __shared__ float red[8][16][68];                // 34816 B full-width reduce
  const int t = threadIdx.x;
  const int w = t >> 6, lane = t & 63;
  const int l16 = lane & 15, l4 = lane >> 4;
  // XCD-aware bijective swizzle (2048 % 8 == 0)
  const int bid = blockIdx.x;
  const int tile = (bid & 7) * 256 + (bid >> 3);
  const int stile = tile & 63;
  const int bh = tile >> 6;
  const int h = bh & 15;
  const int s0 = stile * 16;
  const int maxTile = stile + 33;   // tile pt active iff pt <= maxTile

  float lt = log_temp[h];
  lt = fminf(fmaxf(lt, -4.f), 4.f);
  const float inv_scale = 1.f / (8.f * expf(lt));

  // state B-fragments (swapped mfma): col = l16 = query row, k = 8*l4+j
  const size_t arow = ((size_t)bh * S + s0 + l16) * HD + 8 * l4;
  short8v ahi0 = *(const short8v*)(shi + arow);
  short8v ahi1 = *(const short8v*)(shi + arow + 32);
  short8v alo0 = *(const short8v*)(slo + arow);
  short8v alo1 = *(const short8v*)(slo + arow + 32);

  const size_t kb = (size_t)bh * PT * HD;
  const size_t vb = (size_t)bh * HD * PT;
  const int sg = s0 + l16;

  // ---- QK^T (swapped, interleaved tiles, causal tile-skip) ----
  float z0[6][4], z1[6][4];
#pragma unroll
  for (int j = 0; j < 6; ++j) {
    const int tA = w + 16 * j, tB = tA + 8;
    if (tA > maxTile) {          // whole pair fully masked (wave-uniform)
#pragma unroll
      for (int i = 0; i < 4; ++i) { z0[j][i] = -1e9f; z1[j][i] = -1e9f; }
    } else {
      const size_t k0 = kb + ((size_t)(tA * 16 + l16)) * HD + 8 * l4;
      f32x4 a0 = {0.f, 0.f, 0.f, 0.f};
      {
        short8v b00 = *(const short8v*)(khi + k0);
        short8v b01 = *(const short8v*)(khi + k0 + 32);
        short8v c00 = *(const short8v*)(klo + k0);
        short8v c01 = *(const short8v*)(klo + k0 + 32);
        a0 = __builtin_amdgcn_mfma_f32_16x16x32_bf16(b00, ahi0, a0, 0, 0, 0);
        a0 = __builtin_amdgcn_mfma_f32_16x16x32_bf16(b01, ahi1, a0, 0, 0, 0);
        a0 = __builtin_amdgcn_mfma_f32_16x16x32_bf16(b00, alo0, a0, 0, 0, 0);
        a0 = __builtin_amdgcn_mfma_f32_16x16x32_bf16(b01, alo1, a0, 0, 0, 0);
        a0 = __builtin_amdgcn_mfma_f32_16x16x32_bf16(c00, ahi0, a0, 0, 0, 0);
        a0 = __builtin_amdgcn_mfma_f32_16x16x32_bf16(c01, ahi1, a0, 0, 0, 0);
      }
#pragma unroll
      for (int i = 0; i < 4; ++i) {
        const int pA = tA * 16 + l4 * 4 + i;
        z0[j][i] = (pA > P0 + sg) ? -1e9f : a0[i] * inv_scale;
      }
      if (tB <= maxTile) {
        const size_t k1 = kb + ((size_t)(tB * 16 + l16)) * HD + 8 * l4;
        f32x4 a1 = {0.f, 0.f, 0.f, 0.f};
        short8v b10 = *(const short8v*)(khi + k1);
        short8v b11 = *(const short8v*)(khi + k1 + 32);
        short8v c10 = *(const short8v*)(klo + k1);
        short8v c11 = *(const short8v*)(klo + k1 + 32);
        a1 = __builtin_amdgcn_mfma_f32_16x16x32_bf16(b10, ahi0, a1, 0, 0, 0);
        a1 = __builtin_amdgcn_mfma_f32_16x16x32_bf16(b11, ahi1, a1, 0, 0, 0);
        a1 = __builtin_amdgcn_mfma_f32_16x16x32_bf16(b10, alo0, a1, 0, 0, 0);
        a1 = __builtin_amdgcn_mfma_f32_16x16x32_bf16(b11, alo1, a1, 0, 0, 0);
        a1 = __builtin_amdgcn_mfma_f32_16x16x32_bf16(c10, ahi0, a1, 0, 0, 0);
        a1 = __builtin_amdgcn_mfma_f32_16x16x32_bf16(c11, ahi1, a1, 0, 0, 0);
#pragma unroll
        for (int i = 0; i < 4; ++i) {
          const int pB = tB * 16 + l4 * 4 + i;
          z1[j][i] = (pB > P0 + sg) ? -1e9f : a1[i] * inv_scale;
        }
      } else {
#pragma unroll
        for (int i = 0; i < 4; ++i) z1[j][i] = -1e9f;
      }
    }
  }

  // ---- per-pair maxima (reused by row-max, scan-skip, PV-skip) ----
  float pm[6];
#pragma unroll
  for (int j = 0; j < 6; ++j) {
    pm[j] = fmaxf(fmaxf(fmaxf(z0[j][0], z0[j][1]), fmaxf(z0[j][2], z0[j][3])),
                  fmaxf(fmaxf(z1[j][0], z1[j][1]), fmaxf(z1[j][2], z1[j][3])));
  }

  // ---- row max (over the 6 pair-maxima; masked pairs are -1e9) ----
  float mxv = pm[0];
#pragma unroll
  for (int j = 1; j < 6; ++j) mxv = fmaxf(mxv, pm[j]);
  mxv = fmaxf(mxv, __shfl_xor(mxv, 16, 64));
  mxv = fmaxf(mxv, __shfl_xor(mxv, 32, 64));
  if (lane < 16) part[w][0][0][lane] = mxv;
  __syncthreads();
  float gm = -1e30f;
#pragma unroll
  for (int ww = 0; ww < 8; ++ww) gm = fmaxf(gm, part[ww][0][0][l16]);

  // ---- Michelot from tau0 = gmax-1: 7 rounds, sparsity-guarded scans ----
  float tau = gm - 1.f;
  for (int it = 0; it < 7; ++it) {
    const int sl = (it + 1) & 1;
    float ca = 0.f, cb = 0.f, sa = 0.f, sb = 0.f;
#pragma unroll
    for (int j = 0; j < 6; ++j) {
      if (__any(pm[j] > tau)) {   // monotone tau: dropped pairs stay dropped
#pragma unroll
        for (int i = 0; i < 4; ++i) {
          float a = z0[j][i];
          if (a > tau) { ca += 1.f; sa += a; }
          float b2 = z1[j][i];
          if (b2 > tau) { cb += 1.f; sb += b2; }
        }
      }
    }
    float c = ca + cb, s = sa + sb;
    c += __shfl_xor(c, 16, 64);
    c += __shfl_xor(c, 32, 64);
    s += __shfl_xor(s, 16, 64);
    s += __shfl_xor(s, 32, 64);
    if (lane < 16) {
      part[w][sl][0][lane] = c;
      part[w][sl][1][lane] = s;
    }
    __syncthreads();
    float rc = 0.f, rs = 0.f;
#pragma unroll
    for (int ww = 0; ww < 8; ++ww) {
      rc += part[ww][sl][0][l16];
      rs += part[ww][sl][1][l16];
    }
    tau = (rs - 1.f) / rc;
  }

  // ---- PV: sparsity-skip + in-register weight exchange + 3-prod MFMA ----
  f32x4 acc[4];
#pragma unroll
  for (int dt = 0; dt < 4; ++dt) acc[dt] = (f32x4){0.f, 0.f, 0.f, 0.f};
#pragma unroll
  for (int kk = 0; kk < 6; ++kk) {
    const int tA = w + 16 * kk, tB = tA + 8;
    if (!__any(pm[kk] > tau)) continue;   // all 256 weights zero
    ushort4v h0v, l0v, h1v, l1v;
#pragma unroll
    for (int i = 0; i < 4; ++i) {
      float w0 = fmaxf(z0[kk][i] - tau, 0.f);
      float w1 = fmaxf(z1[kk][i] - tau, 0.f);
      unsigned short hb0 = bf16_rne(w0);
      unsigned short hb1 = bf16_rne(w1);
      h0v[i] = hb0; l0v[i] = bf16_rne(w0 - bf16_f(hb0));
      h1v[i] = hb1; l1v[i] = bf16_rne(w1 - bf16_f(hb1));
    }
    const ull P0v = __builtin_bit_cast(ull, h0v);
    const ull P1v = __builtin_bit_cast(ull, h1v);
    const ull Q0v = __builtin_bit_cast(ull, l0v);
    const ull Q1v = __builtin_bit_cast(ull, l1v);
    const int srcA = l16 + 16 * (2 * (l4 & 1));
    const int srcB = srcA + 16;
    ull a0 = __shfl(P0v, srcA, 64);
    ull a1 = __shfl(P1v, srcA, 64);
    ull b0 = __shfl(P0v, srcB, 64);
    ull b1 = __shfl(P1v, srcB, 64);
    ull qa0 = __shfl(Q0v, srcA, 64);
    ull qa1 = __shfl(Q1v, srcA, 64);
    ull qb0 = __shfl(Q0v, srcB, 64);
    ull qb1 = __shfl(Q1v, srcB, 64);
    ull2 th = { (l4 < 2) ? a0 : a1, (l4 < 2) ? b0 : b1 };
    ull2 tl = { (l4 < 2) ? qa0 : qa1, (l4 < 2) ? qb0 : qb1 };
    short8v wah = __builtin_bit_cast(short8v, th);
    short8v wal = __builtin_bit_cast(short8v, tl);
    // permuted k-order: lanes l4<2 read tile A's p-range, l4>=2 tile B's
    const int pbase = (l4 < 2) ? (tA * 16 + 8 * l4) : (tB * 16 + 8 * (l4 - 2));
#pragma unroll
    for (int dt = 0; dt < 4; ++dt) {
      const size_t vo = vb + (size_t)(dt * 16 + l16) * PT + pbase;
      short8v vh = *(const short8v*)(vthi + vo);
      short8v vl = *(const short8v*)(vtlo + vo);
      acc[dt] = __builtin_amdgcn_mfma_f32_16x16x32_bf16(wah, vh, acc[dt], 0, 0, 0);
      acc[dt] = __builtin_amdgcn_mfma_f32_16x16x32_bf16(wah, vl, acc[dt], 0, 0, 0);
      acc[dt] = __builtin_amdgcn_mfma_f32_16x16x32_bf16(wal, vh, acc[dt], 0, 0, 0);
    }
  }

  // ---- full-width cross-wave reduce (1 barrier) + writes ----
#pragma unroll
  for (int dt = 0; dt < 4; ++dt)
#pragma unroll
    for (int i = 0; i < 4; ++i)
      red[w][l4 * 4 + i][dt * 16 + l16] = acc[dt][i];
  __syncthreads();
  for (int e = t; e < 16 * HD; e += 512) {
    const int row = e >> 6, d = e & 63;
    float sum = 0.f;
#pragma unroll
    for (int ww = 0; ww < 8; ++ww) sum += red[ww][row][d];
    const int sgr = s0 + row;
    unsigned short hb = bf16_rne(sum);
    unsigned short lb = bf16_rne(sum - bf16_f(hb));
    const size_t rw = ((size_t)((bh >> 4) * S + sgr)) * DIM + h * HD + d;
    swhi[rw] = hb;
    swlo[rw] = lb;
    const size_t oi = ((size_t)bh * S + sgr) * HD + d;
    ohi[oi] = hb;
    olo[oi] = lb;
  }
}

// ----------------------------------------------------------- layernorm ----
__global__ __launch_bounds__(256) void k_layernorm(float* __restrict__ out,
                                                   const float* __restrict__ gamma,
                                                   const float* __restrict__ beta) {
  const int W = 2 * DIM;
  const int r = blockIdx.x;
  float* row = out + (size_t)r * W;
  const int t = threadIdx.x;
  float4 vals[2];
  float sum = 0.f, sq = 0.f;
#pragma unroll
  for (int i = 0; i < 2; ++i) {
    float4 v = *(const float4*)(row + (i * 256 + t) * 4);
    vals[i] = v;
    sum += v.x + v.y + v.z + v.w;
    sq += v.x * v.x + v.y * v.y + v.z * v.z + v.w * v.w;
  }
#pragma unroll
  for (int off = 32; off >= 1; off >>= 1) {
    sum += __shfl_xor(sum, off, 64);
    sq  += __shfl_xor(sq,  off, 64);
  }
  __shared__ float rs[4], rq[4];
  const int wave = t >> 6, lane = t & 63;
  if (lane == 0) { rs[wave] = sum; rq[wave] = sq; }
  __syncthreads();
  sum = rs[0] + rs[1] + rs[2] + rs[3];
  sq  = rq[0] + rq[1] + rq[2] + rq[3];
  const float mean = sum / W;
  const float var = sq / W - mean * mean;
  const float rstd = rsqrtf(var + 1e-5f);
#pragma unroll
  for (int i = 0; i < 2; ++i) {
    int base = (i * 256 + t) * 4;
    float4 v = vals[i];
    float4 g = *(const float4*)(gamma + base);
    float4 bb = *(const float4*)(beta + base);
    v.x = (v.x - mean) * rstd * g.x + bb.x;
    v.y = (v.y - mean) * rstd * g.y + bb.y;
    v.z = (v.z - mean) * rstd * g.z + bb.z;
    v.w = (v.w - mean) * rstd * g.w + bb.w;
    *(float4*)(row + base) = v;
  }
}

// ---------------------------------------------------------------- launch --
extern "C" void kernel_launch(void* const* d_in, const int* in_sizes, int n_in,
                              void* d_out, int out_size, void* d_ws, size_t ws_size,
                              hipStream_t stream) {
  const float* zr       = (const float*)d_in[0];
  const float* zi       = (const float*)d_in[1];
  const float* stored   = (const float*)d_in[3];
  const float* Wq       = (const float*)d_in[4];
  const float* Wk       = (const float*)d_in[5];
  const float* Wv       = (const float*)d_in[6];
  const float* Wo       = (const float*)d_in[7];
  const float* bo       = (const float*)d_in[8];
  const float* log_temp = (const float*)d_in[9];
  const float* gamma    = (const float*)d_in[10];
  const float* beta     = (const float*)d_in[11];
  float* out = (float*)d_out;

  // --- workspace layout, 64 MB peak with lifetime overlays ---
  char* base = (char*)d_ws;
  unsigned short* vthi = (unsigned short*)(base + (size_t)0);     // 0-6
  unsigned short* vtlo = (unsigned short*)(base + (6u << 20));    // 6-12
  unsigned short* phi  = (unsigned short*)(base + (12u << 20));   // 12-18
  unsigned short* plo  = (unsigned short*)(base + (18u << 20));   // 18-24
  unsigned short* swhi = (unsigned short*)(base + (12u << 20));   // 12-16 (over dead phi/plo)
  unsigned short* swlo = (unsigned short*)(base + (16u << 20));   // 16-20
  unsigned short* wqh  = (unsigned short*)(base + (24u << 20));   // 24-26
  unsigned short* wql  = (unsigned short*)(base + (26u << 20));   // 26-28
  unsigned short* wkh  = (unsigned short*)(base + (28u << 20));   // 28-30
  unsigned short* wkl  = (unsigned short*)(base + (30u << 20));   // 30-32
  unsigned short* wvh  = (unsigned short*)(base + (32u << 20));   // 32-34
  unsigned short* wvl  = (unsigned short*)(base + (34u << 20));   // 34-36
  unsigned short* woh  = (unsigned short*)(base + (24u << 20));   // 24-28 (over dead wq/wk)
  unsigned short* wol  = (unsigned short*)(base + (28u << 20));   // 28-32
  float* mag = (float*)(base + (36u << 20));                      // 36-44
  unsigned short* qhi = (unsigned short*)(base + (36u << 20));    // 36-40 (over dead mag)
  unsigned short* qlo = (unsigned short*)(base + (40u << 20));    // 40-44
  unsigned short* s1hi = (unsigned short*)(base + (44u << 20));   // 44-48
  unsigned short* s1lo = (unsigned short*)(base + (48u << 20));   // 48-52
  unsigned short* khi  = (unsigned short*)(base + (52u << 20));   // 52-58
  unsigned short* klo  = (unsigned short*)(base + (58u << 20));   // 58-64

  const int n4 = B * S * DIM / 4;            // 524288
  k_mag<<<(n4 + 255) / 256, 256, 0, stream>>>(zr, zi, mag, n4);
  const int p4 = B * PT * DIM / 4;           // 786432
  // pattern build + hi/lo split fused
  k_patt_split<<<(p4 + 255) / 256, 256, 0, stream>>>(stored, mag, phi, plo, p4);

  const int w4 = DIM * DIM / 4;              // 262144
  k_split_plain<<<w4 / 256, 256, 0, stream>>>(Wq, wqh, wql, w4);
  k_split_plain<<<w4 / 256, 256, 0, stream>>>(Wk, wkh, wkl, w4);
  k_split_plain<<<w4 / 256, 256, 0, stream>>>(Wv, wvh, wvl, w4);

  // Q = mag @ Wq^T  (A rows remapped into patt), head-major hi/lo out
  dim3 gq(1024 / 128, 2048 / 128);
  k_gemm_mfma<<<gq, 256, 0, stream>>>(phi, plo, wqh, wql, nullptr, nullptr,
                                      qhi, qlo, 2048, 1024, 1024, 1, 1024, 1);
  // K = patt @ Wk^T, head-major hi/lo out
  dim3 gkv(1024 / 128, 3072 / 128);
  k_gemm_mfma<<<gkv, 256, 0, stream>>>(phi, plo, wkh, wkl, nullptr, nullptr,
                                       khi, klo, 3072, 1024, 1024, 1, 1536, 0);
  // V = patt @ Wv^T, V^T hi/lo out
  k_gemm_mfma<<<gkv, 256, 0, stream>>>(phi, plo, wvh, wvl, nullptr, nullptr,
                                       vthi, vtlo, 3072, 1024, 1024, 2, 1536, 0);

  // Wo split (after wq/wk dead)
  const int wo4 = 2 * DIM * DIM / 4;         // 524288
  k_split_plain<<<wo4 / 256, 256, 0, stream>>>(Wo, woh, wol, wo4);

  const int ablocks = B * H * (S / 16);      // 2048
  k_attn_mfma<<<ablocks, 512, 0, stream>>>(qhi, qlo, khi, klo, vthi, vtlo,
                                           log_temp, swhi, swlo, s1hi, s1lo);
  k_attn_mfma<<<ablocks, 512, 0, stream>>>(s1hi, s1lo, khi, klo, vthi, vtlo,
                                           log_temp, swhi, swlo, qhi, qlo);
  k_attn_mfma<<<ablocks, 512, 0, stream>>>(qhi, qlo, khi, klo, vthi, vtlo,
                                           log_temp, swhi, swlo, s1hi, s1lo);

  // out = sw @ Wo^T + bo, fp32
  dim3 go(2048 / 128, 2048 / 128);
  k_gemm_mfma<<<go, 256, 0, stream>>>(swhi, swlo, woh, wol, bo, out,
                                      nullptr, nullptr, 2048, 2048, 1024, 0, 0, 0);
  k_layernorm<<<B * S, 256, 0, stream>>>(out, gamma, beta);
}

// Round 17
// 616.440 us; speedup vs baseline: 1.2996x; 1.0043x over previous
//
#include <hip/hip_runtime.h>
#include <math.h>

#define DIM 1024
#define P0 512
#define H 16
#define HD 64
#define B 2
#define S 1024
#define PT 1536   // P0 + S

typedef __attribute__((ext_vector_type(8))) short short8v;    // bf16 MFMA frag
typedef __attribute__((ext_vector_type(4))) float f32x4;
typedef __attribute__((ext_vector_type(8))) unsigned short ushort8v;
typedef __attribute__((ext_vector_type(4))) unsigned short ushort4v;
typedef unsigned long long ull;
struct ull2 { ull a, b; };   // 16B carrier for short8v bit_cast

__device__ __forceinline__ unsigned short bf16_rne(float x) {
  unsigned u = __builtin_bit_cast(unsigned, x);
  u += 0x7FFFu + ((u >> 16) & 1u);
  return (unsigned short)(u >> 16);
}
__device__ __forceinline__ float bf16_f(unsigned short h) {
  unsigned u = ((unsigned)h) << 16;
  return __builtin_bit_cast(float, u);
}

// -------------------- pattern build (mag fused) + hi/lo split ------------
// Rows [0,P0) = stored_patterns; rows [P0,PT) = |z| computed inline from
// zr/zi (the fp32 mag buffer is never materialized; Q-GEMM reads these
// rows back through the aremap path).
__global__ __launch_bounds__(256) void k_patt_split(const float* __restrict__ stored,
                                                    const float* __restrict__ zr,
                                                    const float* __restrict__ zi,
                                                    unsigned short* __restrict__ phi,
                                                    unsigned short* __restrict__ plo,
                                                    int n4) {
  int i = blockIdx.x * blockDim.x + threadIdx.x;
  if (i >= n4) return;
  int d4 = i & (DIM / 4 - 1);
  int p  = (i >> 8) % PT;
  int b  = i / (PT * (DIM / 4));
  float4 v;
  if (p < P0) {
    v = ((const float4*)stored)[(size_t)p * (DIM / 4) + d4];
  } else {
    size_t ri = ((size_t)(b * S + (p - P0))) * (DIM / 4) + d4;
    float4 a = ((const float4*)zr)[ri];
    float4 c = ((const float4*)zi)[ri];
    v.x = sqrtf(a.x * a.x + c.x * c.x);
    v.y = sqrtf(a.y * a.y + c.y * c.y);
    v.z = sqrtf(a.z * a.z + c.z * c.z);
    v.w = sqrtf(a.w * a.w + c.w * c.w);
  }
  float xs[4] = {v.x, v.y, v.z, v.w};
  ushort4v hv, lv;
#pragma unroll
  for (int j = 0; j < 4; ++j) {
    unsigned short hb = bf16_rne(xs[j]);
    hv[j] = hb;
    lv[j] = bf16_rne(xs[j] - bf16_f(hb));
  }
  ((ushort4v*)phi)[(size_t)i] = hv;
  ((ushort4v*)plo)[(size_t)i] = lv;
}

// ---------------------------------------------- plain hi/lo bf16 split ----
__global__ __launch_bounds__(256) void k_split_plain(const float* __restrict__ X,
                                                     unsigned short* __restrict__ hi,
                                                     unsigned short* __restrict__ lo,
                                                     int n4) {
  int i = blockIdx.x * 256 + threadIdx.x;
  if (i >= n4) return;
  float4 v = ((const float4*)X)[(size_t)i];
  float xs[4] = {v.x, v.y, v.z, v.w};
  ushort4v hv, lv;
#pragma unroll
  for (int j = 0; j < 4; ++j) {
    unsigned short hb = bf16_rne(xs[j]);
    hv[j] = hb;
    lv[j] = bf16_rne(xs[j] - bf16_f(hb));
  }
  ((ushort4v*)hi)[(size_t)i] = hv;
  ((ushort4v*)lo)[(size_t)i] = lv;
}

// ------------------------------------------------------- MFMA GEMM --------
// C(M,N) = A @ W^T with A,W pre-split hi/lo bf16 row-major (K-contig).
// 128x128 tile, BK=32, 256 threads = 4 waves (2x2), 3-product split.
// (256,3): 12 waves/CU (was 8) for latency hiding; reg demand ~150 fits
// the ~170 cap. Spill sentinel: gemm FETCH/WRITE sizes + total regression.
__global__ __launch_bounds__(256, 3) void k_gemm_mfma(
    const unsigned short* __restrict__ Ah, const unsigned short* __restrict__ Al,
    const unsigned short* __restrict__ Wh, const unsigned short* __restrict__ Wl,
    const float* __restrict__ bias, float* __restrict__ Cf,
    unsigned short* __restrict__ Ohi, unsigned short* __restrict__ Olo,
    int M, int N, int K, int mode, int rpb, int aremap) {
  __shared__ short8v lds[4][4 * 132];   // Ah, Al, Wh, Wl frag-major tiles
  const int t = threadIdx.x;
  const int w = t >> 6, lane = t & 63;
  const int l16 = lane & 15, l4 = lane >> 4;
  const int wr = w >> 1, wc = w & 1;
  const int bm = blockIdx.y, bn = blockIdx.x;

  f32x4 acc[4][4];
#pragma unroll
  for (int mi = 0; mi < 4; ++mi)
#pragma unroll
    for (int nj = 0; nj < 4; ++nj) acc[mi][nj] = (f32x4){0.f, 0.f, 0.f, 0.f};

  for (int k0 = 0; k0 < K; k0 += 32) {
    __syncthreads();
#pragma unroll
    for (int rep = 0; rep < 2; ++rep) {
      int u = rep * 256 + t;
      int kb = u & 3, r = u >> 2;
      int agr = bm * 128 + r;
      int ar = aremap ? (agr + 512 + ((agr >> 10) << 9)) : agr;
      size_t ga = (size_t)ar * K + k0 + kb * 8;
      size_t gw = (size_t)(bn * 128 + r) * K + k0 + kb * 8;
      int li = kb * 132 + r;
      lds[0][li] = *(const short8v*)(Ah + ga);
      lds[1][li] = *(const short8v*)(Al + ga);
      lds[2][li] = *(const short8v*)(Wh + gw);
      lds[3][li] = *(const short8v*)(Wl + gw);
    }
    __syncthreads();
    short8v af[4][2], bf[4][2];
#pragma unroll
    for (int mi = 0; mi < 4; ++mi) {
      int li = l4 * 132 + wr * 64 + mi * 16 + l16;
      af[mi][0] = lds[0][li];
      af[mi][1] = lds[1][li];
    }
#pragma unroll
    for (int nj = 0; nj < 4; ++nj) {
      int li = l4 * 132 + wc * 64 + nj * 16 + l16;
      bf[nj][0] = lds[2][li];
      bf[nj][1] = lds[3][li];
    }
#pragma unroll
    for (int mi = 0; mi < 4; ++mi)
#pragma unroll
      for (int nj = 0; nj < 4; ++nj) {
        acc[mi][nj] = __builtin_amdgcn_mfma_f32_16x16x32_bf16(af[mi][0], bf[nj][0], acc[mi][nj], 0, 0, 0);
        acc[mi][nj] = __builtin_amdgcn_mfma_f32_16x16x32_bf16(af[mi][0], bf[nj][1], acc[mi][nj], 0, 0, 0);
        acc[mi][nj] = __builtin_amdgcn_mfma_f32_16x16x32_bf16(af[mi][1], bf[nj][0], acc[mi][nj], 0, 0, 0);
      }
  }

#pragma unroll
  for (int mi = 0; mi < 4; ++mi)
#pragma unroll
    for (int nj = 0; nj < 4; ++nj)
#pragma unroll
      for (int i = 0; i < 4; ++i) {
        int rg = bm * 128 + wr * 64 + mi * 16 + l4 * 4 + i;
        int c  = bn * 128 + wc * 64 + nj * 16 + l16;
        float v = acc[mi][nj][i];
        if (mode == 0) {
          Cf[(size_t)rg * N + c] = v + (bias ? bias[c] : 0.f);
        } else {
          int b = rg >= rpb ? 1 : 0;
          int p = rg - b * rpb;
          int hh = c >> 6, d = c & 63;
          size_t o = (mode == 1)
                         ? ((((size_t)(b * 16 + hh)) * rpb + p) * 64 + d)
                         : ((((size_t)(b * 16 + hh)) * 64 + d) * (size_t)rpb + p);
          unsigned short hb = bf16_rne(v);
          Ohi[o] = hb;
          Olo[o] = bf16_rne(v - bf16_f(hb));
        }
      }
}

// ------------------------------------------------- MFMA attention step ----
// One Hopfield iteration. Block = 16 query rows of one (b,h), 8 waves.
// Round-16 structure (measured floor ~148us/dispatch): swapped QK^T,
// interleaved tile ownership + causal tile-skip, pm[6]-guarded Michelot
// (1 max + 7 rounds from tau0=gmax-1, exact), sparsity-skipped shfl-PV,
// full-width 1-barrier reduce. __launch_bounds__(512,4): HARD (rounds
// 6 & 10 spilled under tighter caps). Sentinel: WRITE_SIZE ~16 MB.
__global__ __launch_bounds__(512, 4) void k_attn_mfma(
    const unsigned short* __restrict__ shi, const unsigned short* __restrict__ slo,
    const unsigned short* __restrict__ khi, const unsigned short* __restrict__ klo,
    const unsigned short* __restrict__ vthi, const unsigned short* __restrict__ vtlo,
    const float* __restrict__ log_temp,
    unsigned short* __restrict__ swhi, unsigned short* __restrict__ swlo,
    unsigned short* __restrict__ ohi, unsigned short* __restrict__ olo) {
  __shared__ float part[8][2][2][20];             // 5120 B reduction scratch
  __shared__ float red[8][16][68];                // 34816 B full-width reduce
  const int t = threadIdx.x;
  const int w = t >> 6, lane = t & 63;
  const int l16 = lane & 15, l4 = lane >> 4;
  // XCD-aware bijective swizzle (2048 % 8 == 0)
  const int bid = blockIdx.x;
  const int tile = (bid & 7) * 256 + (bid >> 3);
  const int stile = tile & 63;
  const int bh = tile >> 6;
  const int h = bh & 15;
  const int s0 = stile * 16;
  const int maxTile = stile + 33;   // tile pt active iff pt <= maxTile

  float lt = log_temp[h];
  lt = fminf(fmaxf(lt, -4.f), 4.f);
  const float inv_scale = 1.f / (8.f * expf(lt));

  // state B-fragments (swapped mfma): col = l16 = query row, k = 8*l4+j
  const size_t arow = ((size_t)bh * S + s0 + l16) * HD + 8 * l4;
  short8v ahi0 = *(const short8v*)(shi + arow);
  short8v ahi1 = *(const short8v*)(shi + arow + 32);
  short8v alo0 = *(const short8v*)(slo + arow);
  short8v alo1 = *(const short8v*)(slo + arow + 32);

  const size_t kb = (size_t)bh * PT * HD;
  const size_t vb = (size_t)bh * HD * PT;
  const int sg = s0 + l16;

  // ---- QK^T (swapped, interleaved tiles, causal tile-skip) ----
  float z0[6][4], z1[6][4];
#pragma unroll
  for (int j = 0; j < 6; ++j) {
    const int tA = w + 16 * j, tB = tA + 8;
    if (tA > maxTile) {          // whole pair fully masked (wave-uniform)
#pragma unroll
      for (int i = 0; i < 4; ++i) { z0[j][i] = -1e9f; z1[j][i] = -1e9f; }
    } else {
      const size_t k0 = kb + ((size_t)(tA * 16 + l16)) * HD + 8 * l4;
      f32x4 a0 = {0.f, 0.f, 0.f, 0.f};
      {
        short8v b00 = *(const short8v*)(khi + k0);
        short8v b01 = *(const short8v*)(khi + k0 + 32);
        short8v c00 = *(const short8v*)(klo + k0);
        short8v c01 = *(const short8v*)(klo + k0 + 32);
        a0 = __builtin_amdgcn_mfma_f32_16x16x32_bf16(b00, ahi0, a0, 0, 0, 0);
        a0 = __builtin_amdgcn_mfma_f32_16x16x32_bf16(b01, ahi1, a0, 0, 0, 0);
        a0 = __builtin_amdgcn_mfma_f32_16x16x32_bf16(b00, alo0, a0, 0, 0, 0);
        a0 = __builtin_amdgcn_mfma_f32_16x16x32_bf16(b01, alo1, a0, 0, 0, 0);
        a0 = __builtin_amdgcn_mfma_f32_16x16x32_bf16(c00, ahi0, a0, 0, 0, 0);
        a0 = __builtin_amdgcn_mfma_f32_16x16x32_bf16(c01, ahi1, a0, 0, 0, 0);
      }
#pragma unroll
      for (int i = 0; i < 4; ++i) {
        const int pA = tA * 16 + l4 * 4 + i;
        z0[j][i] = (pA > P0 + sg) ? -1e9f : a0[i] * inv_scale;
      }
      if (tB <= maxTile) {
        const size_t k1 = kb + ((size_t)(tB * 16 + l16)) * HD + 8 * l4;
        f32x4 a1 = {0.f, 0.f, 0.f, 0.f};
        short8v b10 = *(const short8v*)(khi + k1);
        short8v b11 = *(const short8v*)(khi + k1 + 32);
        short8v c10 = *(const short8v*)(klo + k1);
        short8v c11 = *(const short8v*)(klo + k1 + 32);
        a1 = __builtin_amdgcn_mfma_f32_16x16x32_bf16(b10, ahi0, a1, 0, 0, 0);
        a1 = __builtin_amdgcn_mfma_f32_16x16x32_bf16(b11, ahi1, a1, 0, 0, 0);
        a1 = __builtin_amdgcn_mfma_f32_16x16x32_bf16(b10, alo0, a1, 0, 0, 0);
        a1 = __builtin_amdgcn_mfma_f32_16x16x32_bf16(b11, alo1, a1, 0, 0, 0);
        a1 = __builtin_amdgcn_mfma_f32_16x16x32_bf16(c10, ahi0, a1, 0, 0, 0);
        a1 = __builtin_amdgcn_mfma_f32_16x16x32_bf16(c11, ahi1, a1, 0, 0, 0);
#pragma unroll
        for (int i = 0; i < 4; ++i) {
          const int pB = tB * 16 + l4 * 4 + i;
          z1[j][i] = (pB > P0 + sg) ? -1e9f : a1[i] * inv_scale;
        }
      } else {
#pragma unroll
        for (int i = 0; i < 4; ++i) z1[j][i] = -1e9f;
      }
    }
  }

  // ---- per-pair maxima (reused by row-max, scan-skip, PV-skip) ----
  float pm[6];
#pragma unroll
  for (int j = 0; j < 6; ++j) {
    pm[j] = fmaxf(fmaxf(fmaxf(z0[j][0], z0[j][1]), fmaxf(z0[j][2], z0[j][3])),
                  fmaxf(fmaxf(z1[j][0], z1[j][1]), fmaxf(z1[j][2], z1[j][3])));
  }

  // ---- row max (over the 6 pair-maxima; masked pairs are -1e9) ----
  float mxv = pm[0];
#pragma unroll
  for (int j = 1; j < 6; ++j) mxv = fmaxf(mxv, pm[j]);
  mxv = fmaxf(mxv, __shfl_xor(mxv, 16, 64));
  mxv = fmaxf(mxv, __shfl_xor(mxv, 32, 64));
  if (lane < 16) part[w][0][0][lane] = mxv;
  __syncthreads();
  float gm = -1e30f;
#pragma unroll
  for (int ww = 0; ww < 8; ++ww) gm = fmaxf(gm, part[ww][0][0][l16]);

  // ---- Michelot from tau0 = gmax-1: 7 rounds, sparsity-guarded scans ----
  float tau = gm - 1.f;
  for (int it = 0; it < 7; ++it) {
    const int sl = (it + 1) & 1;
    float ca = 0.f, cb = 0.f, sa = 0.f, sb = 0.f;
#pragma unroll
    for (int j = 0; j < 6; ++j) {
      if (__any(pm[j] > tau)) {   // monotone tau: dropped pairs stay dropped
#pragma unroll
        for (int i = 0; i < 4; ++i) {
          float a = z0[j][i];
          if (a > tau) { ca += 1.f; sa += a; }
          float b2 = z1[j][i];
          if (b2 > tau) { cb += 1.f; sb += b2; }
        }
      }
    }
    float c = ca + cb, s = sa + sb;
    c += __shfl_xor(c, 16, 64);
    c += __shfl_xor(c, 32, 64);
    s += __shfl_xor(s, 16, 64);
    s += __shfl_xor(s, 32, 64);
    if (lane < 16) {
      part[w][sl][0][lane] = c;
      part[w][sl][1][lane] = s;
    }
    __syncthreads();
    float rc = 0.f, rs = 0.f;
#pragma unroll
    for (int ww = 0; ww < 8; ++ww) {
      rc += part[ww][sl][0][l16];
      rs += part[ww][sl][1][l16];
    }
    tau = (rs - 1.f) / rc;
  }

  // ---- PV: sparsity-skip + in-register weight exchange + 3-prod MFMA ----
  f32x4 acc[4];
#pragma unroll
  for (int dt = 0; dt < 4; ++dt) acc[dt] = (f32x4){0.f, 0.f, 0.f, 0.f};
#pragma unroll
  for (int kk = 0; kk < 6; ++kk) {
    const int tA = w + 16 * kk, tB = tA + 8;
    if (!__any(pm[kk] > tau)) continue;   // all 256 weights zero
    ushort4v h0v, l0v, h1v, l1v;
#pragma unroll
    for (int i = 0; i < 4; ++i) {
      float w0 = fmaxf(z0[kk][i] - tau, 0.f);
      float w1 = fmaxf(z1[kk][i] - tau, 0.f);
      unsigned short hb0 = bf16_rne(w0);
      unsigned short hb1 = bf16_rne(w1);
      h0v[i] = hb0; l0v[i] = bf16_rne(w0 - bf16_f(hb0));
      h1v[i] = hb1; l1v[i] = bf16_rne(w1 - bf16_f(hb1));
    }
    const ull P0v = __builtin_bit_cast(ull, h0v);
    const ull P1v = __builtin_bit_cast(ull, h1v);
    const ull Q0v = __builtin_bit_cast(ull, l0v);
    const ull Q1v = __builtin_bit_cast(ull, l1v);
    const int srcA = l16 + 16 * (2 * (l4 & 1));
    const int srcB = srcA + 16;
    ull a0 = __shfl(P0v, srcA, 64);
    ull a1 = __shfl(P1v, srcA, 64);
    ull b0 = __shfl(P0v, srcB, 64);
    ull b1 = __shfl(P1v, srcB, 64);
    ull qa0 = __shfl(Q0v, srcA, 64);
    ull qa1 = __shfl(Q1v, srcA, 64);
    ull qb0 = __shfl(Q0v, srcB, 64);
    ull qb1 = __shfl(Q1v, srcB, 64);
    ull2 th = { (l4 < 2) ? a0 : a1, (l4 < 2) ? b0 : b1 };
    ull2 tl = { (l4 < 2) ? qa0 : qa1, (l4 < 2) ? qb0 : qb1 };
    short8v wah = __builtin_bit_cast(short8v, th);
    short8v wal = __builtin_bit_cast(short8v, tl);
    // permuted k-order: lanes l4<2 read tile A's p-range, l4>=2 tile B's
    const int pbase = (l4 < 2) ? (tA * 16 + 8 * l4) : (tB * 16 + 8 * (l4 - 2));
#pragma unroll
    for (int dt = 0; dt < 4; ++dt) {
      const size_t vo = vb + (size_t)(dt * 16 + l16) * PT + pbase;
      short8v vh = *(const short8v*)(vthi + vo);
      short8v vl = *(const short8v*)(vtlo + vo);
      acc[dt] = __builtin_amdgcn_mfma_f32_16x16x32_bf16(wah, vh, acc[dt], 0, 0, 0);
      acc[dt] = __builtin_amdgcn_mfma_f32_16x16x32_bf16(wah, vl, acc[dt], 0, 0, 0);
      acc[dt] = __builtin_amdgcn_mfma_f32_16x16x32_bf16(wal, vh, acc[dt], 0, 0, 0);
    }
  }

  // ---- full-width cross-wave reduce (1 barrier) + writes ----
#pragma unroll
  for (int dt = 0; dt < 4; ++dt)
#pragma unroll
    for (int i = 0; i < 4; ++i)
      red[w][l4 * 4 + i][dt * 16 + l16] = acc[dt][i];
  __syncthreads();
  for (int e = t; e < 16 * HD; e += 512) {
    const int row = e >> 6, d = e & 63;
    float sum = 0.f;
#pragma unroll
    for (int ww = 0; ww < 8; ++ww) sum += red[ww][row][d];
    const int sgr = s0 + row;
    unsigned short hb = bf16_rne(sum);
    unsigned short lb = bf16_rne(sum - bf16_f(hb));
    const size_t rw = ((size_t)((bh >> 4) * S + sgr)) * DIM + h * HD + d;
    swhi[rw] = hb;
    swlo[rw] = lb;
    const size_t oi = ((size_t)bh * S + sgr) * HD + d;
    ohi[oi] = hb;
    olo[oi] = lb;
  }
}

// ----------------------------------------------------------- layernorm ----
__global__ __launch_bounds__(256) void k_layernorm(float* __restrict__ out,
                                                   const float* __restrict__ gamma,
                                                   const float* __restrict__ beta) {
  const int W = 2 * DIM;
  const int r = blockIdx.x;
  float* row = out + (size_t)r * W;
  const int t = threadIdx.x;
  float4 vals[2];
  float sum = 0.f, sq = 0.f;
#pragma unroll
  for (int i = 0; i < 2; ++i) {
    float4 v = *(const float4*)(row + (i * 256 + t) * 4);
    vals[i] = v;
    sum += v.x + v.y + v.z + v.w;
    sq += v.x * v.x + v.y * v.y + v.z * v.z + v.w * v.w;
  }
#pragma unroll
  for (int off = 32; off >= 1; off >>= 1) {
    sum += __shfl_xor(sum, off, 64);
    sq  += __shfl_xor(sq,  off, 64);
  }
  __shared__ float rs[4], rq[4];
  const int wave = t >> 6, lane = t & 63;
  if (lane == 0) { rs[wave] = sum; rq[wave] = sq; }
  __syncthreads();
  sum = rs[0] + rs[1] + rs[2] + rs[3];
  sq  = rq[0] + rq[1] + rq[2] + rq[3];
  const float mean = sum / W;
  const float var = sq / W - mean * mean;
  const float rstd = rsqrtf(var + 1e-5f);
#pragma unroll
  for (int i = 0; i < 2; ++i) {
    int base = (i * 256 + t) * 4;
    float4 v = vals[i];
    float4 g = *(const float4*)(gamma + base);
    float4 bb = *(const float4*)(beta + base);
    v.x = (v.x - mean) * rstd * g.x + bb.x;
    v.y = (v.y - mean) * rstd * g.y + bb.y;
    v.z = (v.z - mean) * rstd * g.z + bb.z;
    v.w = (v.w - mean) * rstd * g.w + bb.w;
    *(float4*)(row + base) = v;
  }
}

// ---------------------------------------------------------------- launch --
extern "C" void kernel_launch(void* const* d_in, const int* in_sizes, int n_in,
                              void* d_out, int out_size, void* d_ws, size_t ws_size,
                              hipStream_t stream) {
  const float* zr       = (const float*)d_in[0];
  const float* zi       = (const float*)d_in[1];
  const float* stored   = (const float*)d_in[3];
  const float* Wq       = (const float*)d_in[4];
  const float* Wk       = (const float*)d_in[5];
  const float* Wv       = (const float*)d_in[6];
  const float* Wo       = (const float*)d_in[7];
  const float* bo       = (const float*)d_in[8];
  const float* log_temp = (const float*)d_in[9];
  const float* gamma    = (const float*)d_in[10];
  const float* beta     = (const float*)d_in[11];
  float* out = (float*)d_out;

  // --- workspace layout, 64 MB peak with lifetime overlays ---
  char* base = (char*)d_ws;
  unsigned short* vthi = (unsigned short*)(base + (size_t)0);     // 0-6
  unsigned short* vtlo = (unsigned short*)(base + (6u << 20));    // 6-12
  unsigned short* phi  = (unsigned short*)(base + (12u << 20));   // 12-18
  unsigned short* plo  = (unsigned short*)(base + (18u << 20));   // 18-24
  unsigned short* swhi = (unsigned short*)(base + (12u << 20));   // 12-16 (over dead phi/plo)
  unsigned short* swlo = (unsigned short*)(base + (16u << 20));   // 16-20
  unsigned short* wqh  = (unsigned short*)(base + (24u << 20));   // 24-26
  unsigned short* wql  = (unsigned short*)(base + (26u << 20));   // 26-28
  unsigned short* wkh  = (unsigned short*)(base + (28u << 20));   // 28-30
  unsigned short* wkl  = (unsigned short*)(base + (30u << 20));   // 30-32
  unsigned short* wvh  = (unsigned short*)(base + (32u << 20));   // 32-34
  unsigned short* wvl  = (unsigned short*)(base + (34u << 20));   // 34-36
  unsigned short* woh  = (unsigned short*)(base + (24u << 20));   // 24-28 (over dead wq/wk)
  unsigned short* wol  = (unsigned short*)(base + (28u << 20));   // 28-32
  unsigned short* qhi = (unsigned short*)(base + (36u << 20));    // 36-40
  unsigned short* qlo = (unsigned short*)(base + (40u << 20));    // 40-44
  unsigned short* s1hi = (unsigned short*)(base + (44u << 20));   // 44-48
  unsigned short* s1lo = (unsigned short*)(base + (48u << 20));   // 48-52
  unsigned short* khi  = (unsigned short*)(base + (52u << 20));   // 52-58
  unsigned short* klo  = (unsigned short*)(base + (58u << 20));   // 58-64

  const int p4 = B * PT * DIM / 4;           // 786432
  // pattern build (mag fused inline) + hi/lo split
  k_patt_split<<<(p4 + 255) / 256, 256, 0, stream>>>(stored, zr, zi, phi, plo, p4);

  const int w4 = DIM * DIM / 4;              // 262144
  k_split_plain<<<w4 / 256, 256, 0, stream>>>(Wq, wqh, wql, w4);
  k_split_plain<<<w4 / 256, 256, 0, stream>>>(Wk, wkh, wkl, w4);
  k_split_plain<<<w4 / 256, 256, 0, stream>>>(Wv, wvh, wvl, w4);

  // Q = mag @ Wq^T  (A rows remapped into patt), head-major hi/lo out
  dim3 gq(1024 / 128, 2048 / 128);
  k_gemm_mfma<<<gq, 256, 0, stream>>>(phi, plo, wqh, wql, nullptr, nullptr,
                                      qhi, qlo, 2048, 1024, 1024, 1, 1024, 1);
  // K = patt @ Wk^T, head-major hi/lo out
  dim3 gkv(1024 / 128, 3072 / 128);
  k_gemm_mfma<<<gkv, 256, 0, stream>>>(phi, plo, wkh, wkl, nullptr, nullptr,
                                       khi, klo, 3072, 1024, 1024, 1, 1536, 0);
  // V = patt @ Wv^T, V^T hi/lo out
  k_gemm_mfma<<<gkv, 256, 0, stream>>>(phi, plo, wvh, wvl, nullptr, nullptr,
                                       vthi, vtlo, 3072, 1024, 1024, 2, 1536, 0);

  // Wo split (after wq/wk dead)
  const int wo4 = 2 * DIM * DIM / 4;         // 524288
  k_split_plain<<<wo4 / 256, 256, 0, stream>>>(Wo, woh, wol, wo4);

  const int ablocks = B * H * (S / 16);      // 2048
  k_attn_mfma<<<ablocks, 512, 0, stream>>>(qhi, qlo, khi, klo, vthi, vtlo,
                                           log_temp, swhi, swlo, s1hi, s1lo);
  k_attn_mfma<<<ablocks, 512, 0, stream>>>(s1hi, s1lo, khi, klo, vthi, vtlo,
                                           log_temp, swhi, swlo, qhi, qlo);
  k_attn_mfma<<<ablocks, 512, 0, stream>>>(qhi, qlo, khi, klo, vthi, vtlo,
                                           log_temp, swhi, swlo, s1hi, s1lo);

  // out = sw @ Wo^T + bo, fp32
  dim3 go(2048 / 128, 2048 / 128);
  k_gemm_mfma<<<go, 256, 0, stream>>>(swhi, swlo, woh, wol, bo, out,
                                      nullptr, nullptr, 2048, 2048, 1024, 0, 0, 0);
  k_layernorm<<<B * S, 256, 0, stream>>>(out, gamma, beta);
}